// Round 1
// baseline (1632.944 us; speedup 1.0000x reference)
//
#include <hip/hip_runtime.h>
#include <cstdint>
#include <cstddef>

#define G 256
#define EPER 4096
#define F 128

__device__ inline void lds_atomic_add(float* p, float v) {
    __hip_atomic_fetch_add(p, v, __ATOMIC_RELAXED, __HIP_MEMORY_SCOPE_WORKGROUP);
}

__device__ inline void fma4(float4& a, float s, const float4& w) {
    a.x = fmaf(s, w.x, a.x);
    a.y = fmaf(s, w.y, a.y);
    a.z = fmaf(s, w.z, a.z);
    a.w = fmaf(s, w.w, a.w);
}

// -------------------- scatter: agg[dst] += x[src] (per graph, LDS) --------------------
template<int NS, bool USE_MAP>
__global__ __launch_bounds__(256) void k_scatter(const float* __restrict__ x,
                                                 const int* __restrict__ src,
                                                 const int* __restrict__ dst,
                                                 const int* __restrict__ cmap,
                                                 float* __restrict__ A) {
    __shared__ float agg[NS * F];
    __shared__ int smap[256];
    const int g = blockIdx.x, t = threadIdx.x;

    float4* a4 = (float4*)agg;
    #pragma unroll
    for (int i = t; i < NS * F / 4; i += 256) a4[i] = float4{0.f, 0.f, 0.f, 0.f};
    if (USE_MAP) smap[t] = cmap[g * 256 + t];
    __syncthreads();

    const int f = t & 127, eo = t >> 7;
    const int* sg = src + (size_t)g * EPER;
    const int* dg = dst + (size_t)g * EPER;
    // stage 1: x rows at g*32768 ; stages 2/3: pooled rows at g*32768 + 16384
    const float* xg = x + (size_t)g * 32768 + (USE_MAP ? 16384 : 0);

    for (int e0 = 0; e0 < EPER; e0 += 8) {
        #pragma unroll
        for (int u = 0; u < 4; ++u) {
            int e = e0 + eo + 2 * u;
            int s = sg[e], d = dg[e];
            if (USE_MAP) {
                s = smap[s]; d = smap[d];
                if ((s | d) < 0) continue;
            }
            lds_atomic_add(&agg[d * F + f], xg[(size_t)s * F + f]);
        }
    }
    __syncthreads();

    float4* Ag = (float4*)(A + (size_t)g * 32768);
    #pragma unroll
    for (int i = t; i < NS * F / 4; i += 256) Ag[i] = a4[i];
}

// -------------------- conv GEMM: A[m,:] = relu(X[m]@Wr + AGG[m]@Wl + b) --------------------
// Treated as one GEMM, K=256 ([X | AGG] rows, [Wr; Wl] weights). BM=128, BN=128.
template<int NS, bool FIRST>
__global__ __launch_bounds__(256) void k_gemm(const float* __restrict__ X,
                                              float* __restrict__ A,
                                              const float* __restrict__ Wr,
                                              const float* __restrict__ Wl,
                                              const float* __restrict__ bias) {
    constexpr int L2NS = (NS == 256) ? 8 : (NS == 128) ? 7 : 6;
    __shared__ float AsT[32 * 128];  // [k][row] transposed A tile
    __shared__ float Ws[32 * 128];   // [k][col] W tile
    const int t = threadIdx.x;
    const int m0 = blockIdx.x * 128;
    const int co = t & 15, rg = t >> 4;  // 16 col-octs x 16 row-groups

    float4 acc[8][2];
    #pragma unroll
    for (int i = 0; i < 8; ++i) {
        acc[i][0] = float4{0.f, 0.f, 0.f, 0.f};
        acc[i][1] = float4{0.f, 0.f, 0.f, 0.f};
    }

    // A-staging: thread t loads row r_st = t>>1, k-quad set (t&1)*16 + q*4
    const int r_st = t >> 1;
    const int m_st = m0 + r_st;
    const int g_st = m_st >> L2NS, n_st = m_st & (NS - 1);
    const float* xrow = FIRST ? (X + (size_t)m_st * F)
                              : (X + (size_t)g_st * 32768 + (size_t)(128 + n_st) * F);
    const float* arow = A + (size_t)g_st * 32768 + (size_t)n_st * F;
    const int kq_base = (t & 1) * 16;

    for (int kt = 0; kt < 8; ++kt) {
        __syncthreads();
        // --- stage A tile (transposed) ---
        const float* srow = (kt < 4) ? (xrow + kt * 32) : (arow + (kt - 4) * 32);
        #pragma unroll
        for (int q = 0; q < 4; ++q) {
            float4 v = *(const float4*)(srow + kq_base + q * 4);
            int kl = kq_base + q * 4;
            AsT[(kl + 0) * 128 + r_st] = v.x;
            AsT[(kl + 1) * 128 + r_st] = v.y;
            AsT[(kl + 2) * 128 + r_st] = v.z;
            AsT[(kl + 3) * 128 + r_st] = v.w;
        }
        // --- stage W tile ---
        const float* wsrc = (kt < 4) ? (Wr + (size_t)kt * 32 * F) : (Wl + (size_t)(kt - 4) * 32 * F);
        {
            const int fu = t & 31;
            #pragma unroll
            for (int q = 0; q < 4; ++q) {
                int k = q * 8 + (t >> 5);
                *(float4*)(Ws + k * 128 + fu * 4) = *(const float4*)(wsrc + (size_t)k * F + fu * 4);
            }
        }
        __syncthreads();

        const float4* AsT4 = (const float4*)AsT;
        const float4* Ws4 = (const float4*)Ws;
        #pragma unroll 4
        for (int k = 0; k < 32; ++k) {
            float4 xa = AsT4[k * 32 + rg * 2];
            float4 xb = AsT4[k * 32 + rg * 2 + 1];
            float4 wa = Ws4[k * 32 + co * 2];
            float4 wb = Ws4[k * 32 + co * 2 + 1];
            fma4(acc[0][0], xa.x, wa); fma4(acc[0][1], xa.x, wb);
            fma4(acc[1][0], xa.y, wa); fma4(acc[1][1], xa.y, wb);
            fma4(acc[2][0], xa.z, wa); fma4(acc[2][1], xa.z, wb);
            fma4(acc[3][0], xa.w, wa); fma4(acc[3][1], xa.w, wb);
            fma4(acc[4][0], xb.x, wa); fma4(acc[4][1], xb.x, wb);
            fma4(acc[5][0], xb.y, wa); fma4(acc[5][1], xb.y, wb);
            fma4(acc[6][0], xb.z, wa); fma4(acc[6][1], xb.z, wb);
            fma4(acc[7][0], xb.w, wa); fma4(acc[7][1], xb.w, wb);
        }
    }

    float4 b0 = *(const float4*)(bias + co * 8);
    float4 b1 = *(const float4*)(bias + co * 8 + 4);
    #pragma unroll
    for (int i = 0; i < 8; ++i) {
        int m = m0 + rg * 8 + i;
        int gg = m >> L2NS, nn = m & (NS - 1);
        float* orow = A + (size_t)gg * 32768 + (size_t)nn * F + co * 8;
        float4 o0, o1;
        o0.x = fmaxf(acc[i][0].x + b0.x, 0.f);
        o0.y = fmaxf(acc[i][0].y + b0.y, 0.f);
        o0.z = fmaxf(acc[i][0].z + b0.z, 0.f);
        o0.w = fmaxf(acc[i][0].w + b0.w, 0.f);
        o1.x = fmaxf(acc[i][1].x + b1.x, 0.f);
        o1.y = fmaxf(acc[i][1].y + b1.y, 0.f);
        o1.z = fmaxf(acc[i][1].z + b1.z, 0.f);
        o1.w = fmaxf(acc[i][1].w + b1.w, 0.f);
        *(float4*)orow = o0;
        *(float4*)(orow + 4) = o1;
    }
}

// -------------------- top-k pool + readout + cmap update --------------------
template<int N, int K, int STAGE>
__global__ __launch_bounds__(256) void k_pool(float* __restrict__ A,
                                              float* __restrict__ R,
                                              int* __restrict__ cmap,
                                              const float* __restrict__ wp) {
    __shared__ float sc[256];
    __shared__ unsigned long long keys[256];
    __shared__ float hp[K * F];
    __shared__ int sel[K];
    __shared__ int inv[N];
    __shared__ float wn[F];
    __shared__ float snorm_s;
    const int g = blockIdx.x, t = threadIdx.x;
    const float* h = A + (size_t)g * 32768;

    if (t < 64) {
        float v = wp[t] * wp[t] + wp[t + 64] * wp[t + 64];
        #pragma unroll
        for (int o = 32; o; o >>= 1) v += __shfl_xor(v, o);
        if (t == 0) snorm_s = sqrtf(v);
    }
    __syncthreads();
    if (t < 128) wn[t] = wp[t] / snorm_s;
    __syncthreads();

    // scores: one wave per node row
    const int wid = t >> 6, lane = t & 63;
    for (int n = wid; n < N; n += 4) {
        float p = h[n * F + lane] * wn[lane] + h[n * F + 64 + lane] * wn[64 + lane];
        #pragma unroll
        for (int o = 32; o; o >>= 1) p += __shfl_xor(p, o);
        if (lane == 0) sc[n] = p;
    }
    __syncthreads();

    // sort keys descending: (order-preserving score bits, ties -> smaller idx first)
    if (t < N) {
        unsigned u = __float_as_uint(sc[t]);
        u = (u & 0x80000000u) ? ~u : (u | 0x80000000u);
        keys[t] = ((unsigned long long)u << 32) | (unsigned)(~t);
    } else {
        keys[t] = 0ull;
    }
    __syncthreads();
    for (int kk = 2; kk <= 256; kk <<= 1) {
        for (int j = kk >> 1; j > 0; j >>= 1) {
            int ixj = t ^ j;
            if (ixj > t) {
                unsigned long long a = keys[t], b = keys[ixj];
                bool up = (t & kk) == 0;
                if (up ? (a < b) : (a > b)) { keys[t] = b; keys[ixj] = a; }
            }
            __syncthreads();
        }
    }

    if (t < K) sel[t] = (int)(~(unsigned)keys[t]);
    if (t < N) inv[t] = -1;
    __syncthreads();
    if (t < K) inv[sel[t]] = t;
    __syncthreads();

    // composed original-node -> current-stage-id map
    {
        int c = (STAGE == 1) ? t : cmap[g * 256 + t];
        cmap[g * 256 + t] = (c >= 0) ? inv[c] : -1;
    }

    // gather gated rows into LDS (all reads of h complete before any global write)
    const int f = t & 127;
    for (int j = t >> 7; j < K; j += 2) {
        int n = sel[j];
        float gate = tanhf(sc[n]);
        hp[j * F + f] = h[n * F + f] * gate;
    }
    __syncthreads();

    if (STAGE < 3) {
        for (int j = t >> 7; j < K; j += 2)
            A[(size_t)g * 32768 + (size_t)(128 + j) * F + f] = hp[j * F + f];
    }

    // readout: max & mean over pooled nodes
    if (t < 128) {
        float mx = -INFINITY, sm = 0.f;
        for (int j = 0; j < K; ++j) {
            float v = hp[j * F + t];
            mx = fmaxf(mx, v);
            sm += v;
        }
        R[(size_t)g * 768 + (STAGE - 1) * 256 + t] = mx;
        R[(size_t)g * 768 + (STAGE - 1) * 256 + 128 + t] = sm * (1.0f / K);
    }
}

// -------------------- final MLP + log_softmax --------------------
__global__ __launch_bounds__(128) void k_mlp(const float* __restrict__ R,
                                             const float* __restrict__ W1, const float* __restrict__ b1,
                                             const float* __restrict__ W2, const float* __restrict__ b2,
                                             const float* __restrict__ W3, const float* __restrict__ b3,
                                             float* __restrict__ out) {
    __shared__ float z[768];
    __shared__ float z2[128];
    __shared__ float z3[64];
    __shared__ float lg[10];
    __shared__ float lse;
    const int g = blockIdx.x, t = threadIdx.x;

    #pragma unroll
    for (int i = 0; i < 6; ++i) z[t + i * 128] = R[(size_t)g * 768 + t + i * 128];
    __syncthreads();

    float acc = b1[t];
    #pragma unroll 8
    for (int k = 0; k < 768; ++k) acc = fmaf(z[k], W1[k * 128 + t], acc);
    z2[t] = fmaxf(acc, 0.f);
    __syncthreads();

    if (t < 64) {
        float a2 = b2[t];
        #pragma unroll 8
        for (int k = 0; k < 128; ++k) a2 = fmaf(z2[k], W2[k * 64 + t], a2);
        z3[t] = fmaxf(a2, 0.f);
    }
    __syncthreads();

    if (t < 10) {
        float a3 = b3[t];
        #pragma unroll 8
        for (int k = 0; k < 64; ++k) a3 = fmaf(z3[k], W3[k * 10 + t], a3);
        lg[t] = a3;
    }
    __syncthreads();

    if (t == 0) {
        float m = lg[0];
        for (int c = 1; c < 10; ++c) m = fmaxf(m, lg[c]);
        float s = 0.f;
        for (int c = 0; c < 10; ++c) s += expf(lg[c] - m);
        lse = m + logf(s);
    }
    __syncthreads();
    if (t < 10) out[(size_t)g * 10 + t] = lg[t] - lse;
}

extern "C" void kernel_launch(void* const* d_in, const int* in_sizes, int n_in,
                              void* d_out, int out_size, void* d_ws, size_t ws_size,
                              hipStream_t stream) {
    (void)in_sizes; (void)n_in; (void)out_size; (void)ws_size;
    const float* x    = (const float*)d_in[0];
    const int*   src  = (const int*)d_in[1];
    const int*   dst  = (const int*)d_in[2];
    const float* Wr1  = (const float*)d_in[3];
    const float* Wrel1= (const float*)d_in[4];
    const float* b1   = (const float*)d_in[5];
    const float* wp1  = (const float*)d_in[6];
    const float* Wr2  = (const float*)d_in[7];
    const float* Wrel2= (const float*)d_in[8];
    const float* b2   = (const float*)d_in[9];
    const float* wp2  = (const float*)d_in[10];
    const float* Wr3  = (const float*)d_in[11];
    const float* Wrel3= (const float*)d_in[12];
    const float* b3   = (const float*)d_in[13];
    const float* wp3  = (const float*)d_in[14];
    const float* L1w  = (const float*)d_in[15];
    const float* L1b  = (const float*)d_in[16];
    const float* L2w  = (const float*)d_in[17];
    const float* L2b  = (const float*)d_in[18];
    const float* L3w  = (const float*)d_in[19];
    const float* L3b  = (const float*)d_in[20];

    float* A    = (float*)d_ws;                                       // G x 256 x 128 f32 (33.5 MB)
    int*   cmap = (int*)((char*)d_ws + (size_t)G * 32768 * 4);        // G x 256 i32
    float* R    = (float*)((char*)d_ws + (size_t)G * 32768 * 4 + (size_t)G * 256 * 4);  // G x 768 f32
    float* out  = (float*)d_out;

    // stage 1
    k_scatter<256, false><<<G, 256, 0, stream>>>(x, src, dst, nullptr, A);
    k_gemm<256, true><<<512, 256, 0, stream>>>(x, A, Wr1, Wrel1, b1);
    k_pool<256, 128, 1><<<G, 256, 0, stream>>>(A, R, cmap, wp1);
    // stage 2
    k_scatter<128, true><<<G, 256, 0, stream>>>(A, src, dst, cmap, A);
    k_gemm<128, false><<<256, 256, 0, stream>>>(A, A, Wr2, Wrel2, b2);
    k_pool<128, 64, 2><<<G, 256, 0, stream>>>(A, R, cmap, wp2);
    // stage 3
    k_scatter<64, true><<<G, 256, 0, stream>>>(A, src, dst, cmap, A);
    k_gemm<64, false><<<128, 256, 0, stream>>>(A, A, Wr3, Wrel3, b3);
    k_pool<64, 32, 3><<<G, 256, 0, stream>>>(A, R, cmap, wp3);
    // head
    k_mlp<<<G, 128, 0, stream>>>(R, L1w, L1b, L2w, L2b, L3w, L3b, out);
}

// Round 2
// 1233.477 us; speedup vs baseline: 1.3239x; 1.3239x over previous
//
#include <hip/hip_runtime.h>
#include <cstdint>
#include <cstddef>

#define G 256
#define EPER 4096
#define F 128

__device__ inline void lds_atomic_add(float* p, float v) {
    __hip_atomic_fetch_add(p, v, __ATOMIC_RELAXED, __HIP_MEMORY_SCOPE_WORKGROUP);
}

__device__ inline void fma4(float4& a, float s, const float4& w) {
    a.x = fmaf(s, w.x, a.x);
    a.y = fmaf(s, w.y, a.y);
    a.z = fmaf(s, w.z, a.z);
    a.w = fmaf(s, w.w, a.w);
}

// -------------------- scatter: agg[dst] += x[src] --------------------
// 4 blocks per graph, each owning a 32-feature slice. agg LDS = NS*32*4 B
// (32 KB at NS=256) -> 4+ blocks/CU instead of 1. 4-edge software pipeline.
template<int NS, bool USE_MAP>
__global__ __launch_bounds__(256) void k_scatter(const float* __restrict__ x,
                                                 const int* __restrict__ src,
                                                 const int* __restrict__ dst,
                                                 const int* __restrict__ cmap,
                                                 float* __restrict__ A) {
    __shared__ float agg[NS * 32];
    __shared__ int smap[256];
    const int b = blockIdx.x, t = threadIdx.x;
    const int g = b >> 2, fc = b & 3;

    float4* a4 = (float4*)agg;
    #pragma unroll
    for (int i = t; i < NS * 8; i += 256) a4[i] = float4{0.f, 0.f, 0.f, 0.f};
    if (USE_MAP) smap[t] = cmap[g * 256 + t];
    __syncthreads();

    const int fl = t & 31, eo = t >> 5;  // 8 edge slots x 32 features
    const int* sg = src + (size_t)g * EPER;
    const int* dg = dst + (size_t)g * EPER;
    // stage 1: x rows at g*32768 ; stages 2/3: pooled rows at g*32768 + 16384
    const float* xg = x + (size_t)g * 32768 + (USE_MAP ? 16384 : 0) + fc * 32 + fl;

    for (int e0 = 0; e0 < EPER; e0 += 32) {
        int s4[4], d4[4];
        bool live[4];
        float v[4];
        #pragma unroll
        for (int u = 0; u < 4; ++u) {
            int e = e0 + u * 8 + eo;
            int s = sg[e], d = dg[e];
            if (USE_MAP) {
                s = smap[s]; d = smap[d];
                live[u] = ((s | d) >= 0);
            } else {
                live[u] = true;
            }
            s4[u] = s; d4[u] = d;
        }
        #pragma unroll
        for (int u = 0; u < 4; ++u)
            if (live[u]) v[u] = xg[(size_t)s4[u] * F];
        #pragma unroll
        for (int u = 0; u < 4; ++u)
            if (live[u]) lds_atomic_add(&agg[d4[u] * 32 + fl], v[u]);
    }
    __syncthreads();

    float4* Ag = (float4*)(A + (size_t)g * 32768);
    #pragma unroll
    for (int i = t; i < NS * 8; i += 256) {
        int n = i >> 3, j = i & 7;
        Ag[n * 32 + fc * 8 + j] = a4[i];
    }
}

// -------------------- conv GEMM: A[m,:] = relu(X[m]@Wr + AGG[m]@Wl + b) --------------------
// Treated as one GEMM, K=256 ([X | AGG] rows, [Wr; Wl] weights). BM=128, BN=128.
template<int NS, bool FIRST>
__global__ __launch_bounds__(256) void k_gemm(const float* __restrict__ X,
                                              float* __restrict__ A,
                                              const float* __restrict__ Wr,
                                              const float* __restrict__ Wl,
                                              const float* __restrict__ bias) {
    constexpr int L2NS = (NS == 256) ? 8 : (NS == 128) ? 7 : 6;
    __shared__ float AsT[32 * 128];  // [k][row] transposed A tile
    __shared__ float Ws[32 * 128];   // [k][col] W tile
    const int t = threadIdx.x;
    const int m0 = blockIdx.x * 128;
    const int co = t & 15, rg = t >> 4;  // 16 col-octs x 16 row-groups

    float4 acc[8][2];
    #pragma unroll
    for (int i = 0; i < 8; ++i) {
        acc[i][0] = float4{0.f, 0.f, 0.f, 0.f};
        acc[i][1] = float4{0.f, 0.f, 0.f, 0.f};
    }

    // A-staging: thread t loads row r_st = t>>1, k-quad set (t&1)*16 + q*4
    const int r_st = t >> 1;
    const int m_st = m0 + r_st;
    const int g_st = m_st >> L2NS, n_st = m_st & (NS - 1);
    const float* xrow = FIRST ? (X + (size_t)m_st * F)
                              : (X + (size_t)g_st * 32768 + (size_t)(128 + n_st) * F);
    const float* arow = A + (size_t)g_st * 32768 + (size_t)n_st * F;
    const int kq_base = (t & 1) * 16;

    for (int kt = 0; kt < 8; ++kt) {
        __syncthreads();
        // --- stage A tile (transposed) ---
        const float* srow = (kt < 4) ? (xrow + kt * 32) : (arow + (kt - 4) * 32);
        #pragma unroll
        for (int q = 0; q < 4; ++q) {
            float4 v = *(const float4*)(srow + kq_base + q * 4);
            int kl = kq_base + q * 4;
            AsT[(kl + 0) * 128 + r_st] = v.x;
            AsT[(kl + 1) * 128 + r_st] = v.y;
            AsT[(kl + 2) * 128 + r_st] = v.z;
            AsT[(kl + 3) * 128 + r_st] = v.w;
        }
        // --- stage W tile ---
        const float* wsrc = (kt < 4) ? (Wr + (size_t)kt * 32 * F) : (Wl + (size_t)(kt - 4) * 32 * F);
        {
            const int fu = t & 31;
            #pragma unroll
            for (int q = 0; q < 4; ++q) {
                int k = q * 8 + (t >> 5);
                *(float4*)(Ws + k * 128 + fu * 4) = *(const float4*)(wsrc + (size_t)k * F + fu * 4);
            }
        }
        __syncthreads();

        const float4* AsT4 = (const float4*)AsT;
        const float4* Ws4 = (const float4*)Ws;
        #pragma unroll 4
        for (int k = 0; k < 32; ++k) {
            float4 xa = AsT4[k * 32 + rg * 2];
            float4 xb = AsT4[k * 32 + rg * 2 + 1];
            float4 wa = Ws4[k * 32 + co * 2];
            float4 wb = Ws4[k * 32 + co * 2 + 1];
            fma4(acc[0][0], xa.x, wa); fma4(acc[0][1], xa.x, wb);
            fma4(acc[1][0], xa.y, wa); fma4(acc[1][1], xa.y, wb);
            fma4(acc[2][0], xa.z, wa); fma4(acc[2][1], xa.z, wb);
            fma4(acc[3][0], xa.w, wa); fma4(acc[3][1], xa.w, wb);
            fma4(acc[4][0], xb.x, wa); fma4(acc[4][1], xb.x, wb);
            fma4(acc[5][0], xb.y, wa); fma4(acc[5][1], xb.y, wb);
            fma4(acc[6][0], xb.z, wa); fma4(acc[6][1], xb.z, wb);
            fma4(acc[7][0], xb.w, wa); fma4(acc[7][1], xb.w, wb);
        }
    }

    float4 b0 = *(const float4*)(bias + co * 8);
    float4 b1 = *(const float4*)(bias + co * 8 + 4);
    #pragma unroll
    for (int i = 0; i < 8; ++i) {
        int m = m0 + rg * 8 + i;
        int gg = m >> L2NS, nn = m & (NS - 1);
        float* orow = A + (size_t)gg * 32768 + (size_t)nn * F + co * 8;
        float4 o0, o1;
        o0.x = fmaxf(acc[i][0].x + b0.x, 0.f);
        o0.y = fmaxf(acc[i][0].y + b0.y, 0.f);
        o0.z = fmaxf(acc[i][0].z + b0.z, 0.f);
        o0.w = fmaxf(acc[i][0].w + b0.w, 0.f);
        o1.x = fmaxf(acc[i][1].x + b1.x, 0.f);
        o1.y = fmaxf(acc[i][1].y + b1.y, 0.f);
        o1.z = fmaxf(acc[i][1].z + b1.z, 0.f);
        o1.w = fmaxf(acc[i][1].w + b1.w, 0.f);
        *(float4*)orow = o0;
        *(float4*)(orow + 4) = o1;
    }
}

// -------------------- top-k pool + readout + cmap update --------------------
template<int N, int K, int STAGE>
__global__ __launch_bounds__(256) void k_pool(float* __restrict__ A,
                                              float* __restrict__ R,
                                              int* __restrict__ cmap,
                                              const float* __restrict__ wp) {
    __shared__ float sc[256];
    __shared__ unsigned long long keys[256];
    __shared__ float hp[K * F];
    __shared__ int sel[K];
    __shared__ int inv[N];
    __shared__ float wn[F];
    __shared__ float snorm_s;
    const int g = blockIdx.x, t = threadIdx.x;
    const float* h = A + (size_t)g * 32768;

    if (t < 64) {
        float v = wp[t] * wp[t] + wp[t + 64] * wp[t + 64];
        #pragma unroll
        for (int o = 32; o; o >>= 1) v += __shfl_xor(v, o);
        if (t == 0) snorm_s = sqrtf(v);
    }
    __syncthreads();
    if (t < 128) wn[t] = wp[t] / snorm_s;
    __syncthreads();

    // scores: one wave per node row
    const int wid = t >> 6, lane = t & 63;
    for (int n = wid; n < N; n += 4) {
        float p = h[n * F + lane] * wn[lane] + h[n * F + 64 + lane] * wn[64 + lane];
        #pragma unroll
        for (int o = 32; o; o >>= 1) p += __shfl_xor(p, o);
        if (lane == 0) sc[n] = p;
    }
    __syncthreads();

    // sort keys descending: (order-preserving score bits, ties -> smaller idx first)
    if (t < N) {
        unsigned u = __float_as_uint(sc[t]);
        u = (u & 0x80000000u) ? ~u : (u | 0x80000000u);
        keys[t] = ((unsigned long long)u << 32) | (unsigned)(~t);
    } else {
        keys[t] = 0ull;
    }
    __syncthreads();
    for (int kk = 2; kk <= 256; kk <<= 1) {
        for (int j = kk >> 1; j > 0; j >>= 1) {
            int ixj = t ^ j;
            if (ixj > t) {
                unsigned long long a = keys[t], b = keys[ixj];
                bool up = (t & kk) == 0;
                if (up ? (a < b) : (a > b)) { keys[t] = b; keys[ixj] = a; }
            }
            __syncthreads();
        }
    }

    if (t < K) sel[t] = (int)(~(unsigned)keys[t]);
    if (t < N) inv[t] = -1;
    __syncthreads();
    if (t < K) inv[sel[t]] = t;
    __syncthreads();

    // composed original-node -> current-stage-id map
    {
        int c = (STAGE == 1) ? t : cmap[g * 256 + t];
        cmap[g * 256 + t] = (c >= 0) ? inv[c] : -1;
    }

    // gather gated rows into LDS (all reads of h complete before any global write)
    const int f = t & 127;
    for (int j = t >> 7; j < K; j += 2) {
        int n = sel[j];
        float gate = tanhf(sc[n]);
        hp[j * F + f] = h[n * F + f] * gate;
    }
    __syncthreads();

    if (STAGE < 3) {
        for (int j = t >> 7; j < K; j += 2)
            A[(size_t)g * 32768 + (size_t)(128 + j) * F + f] = hp[j * F + f];
    }

    // readout: max & mean over pooled nodes
    if (t < 128) {
        float mx = -INFINITY, sm = 0.f;
        for (int j = 0; j < K; ++j) {
            float v = hp[j * F + t];
            mx = fmaxf(mx, v);
            sm += v;
        }
        R[(size_t)g * 768 + (STAGE - 1) * 256 + t] = mx;
        R[(size_t)g * 768 + (STAGE - 1) * 256 + 128 + t] = sm * (1.0f / K);
    }
}

// -------------------- final MLP + log_softmax --------------------
__global__ __launch_bounds__(128) void k_mlp(const float* __restrict__ R,
                                             const float* __restrict__ W1, const float* __restrict__ b1,
                                             const float* __restrict__ W2, const float* __restrict__ b2,
                                             const float* __restrict__ W3, const float* __restrict__ b3,
                                             float* __restrict__ out) {
    __shared__ float z[768];
    __shared__ float z2[128];
    __shared__ float z3[64];
    __shared__ float lg[10];
    __shared__ float lse;
    const int g = blockIdx.x, t = threadIdx.x;

    #pragma unroll
    for (int i = 0; i < 6; ++i) z[t + i * 128] = R[(size_t)g * 768 + t + i * 128];
    __syncthreads();

    float acc = b1[t];
    #pragma unroll 8
    for (int k = 0; k < 768; ++k) acc = fmaf(z[k], W1[k * 128 + t], acc);
    z2[t] = fmaxf(acc, 0.f);
    __syncthreads();

    if (t < 64) {
        float a2 = b2[t];
        #pragma unroll 8
        for (int k = 0; k < 128; ++k) a2 = fmaf(z2[k], W2[k * 64 + t], a2);
        z3[t] = fmaxf(a2, 0.f);
    }
    __syncthreads();

    if (t < 10) {
        float a3 = b3[t];
        #pragma unroll 8
        for (int k = 0; k < 64; ++k) a3 = fmaf(z3[k], W3[k * 10 + t], a3);
        lg[t] = a3;
    }
    __syncthreads();

    if (t == 0) {
        float m = lg[0];
        for (int c = 1; c < 10; ++c) m = fmaxf(m, lg[c]);
        float s = 0.f;
        for (int c = 0; c < 10; ++c) s += expf(lg[c] - m);
        lse = m + logf(s);
    }
    __syncthreads();
    if (t < 10) out[(size_t)g * 10 + t] = lg[t] - lse;
}

extern "C" void kernel_launch(void* const* d_in, const int* in_sizes, int n_in,
                              void* d_out, int out_size, void* d_ws, size_t ws_size,
                              hipStream_t stream) {
    (void)in_sizes; (void)n_in; (void)out_size; (void)ws_size;
    const float* x    = (const float*)d_in[0];
    const int*   src  = (const int*)d_in[1];
    const int*   dst  = (const int*)d_in[2];
    const float* Wr1  = (const float*)d_in[3];
    const float* Wrel1= (const float*)d_in[4];
    const float* b1   = (const float*)d_in[5];
    const float* wp1  = (const float*)d_in[6];
    const float* Wr2  = (const float*)d_in[7];
    const float* Wrel2= (const float*)d_in[8];
    const float* b2   = (const float*)d_in[9];
    const float* wp2  = (const float*)d_in[10];
    const float* Wr3  = (const float*)d_in[11];
    const float* Wrel3= (const float*)d_in[12];
    const float* b3   = (const float*)d_in[13];
    const float* wp3  = (const float*)d_in[14];
    const float* L1w  = (const float*)d_in[15];
    const float* L1b  = (const float*)d_in[16];
    const float* L2w  = (const float*)d_in[17];
    const float* L2b  = (const float*)d_in[18];
    const float* L3w  = (const float*)d_in[19];
    const float* L3b  = (const float*)d_in[20];

    float* A    = (float*)d_ws;                                       // G x 256 x 128 f32 (33.5 MB)
    int*   cmap = (int*)((char*)d_ws + (size_t)G * 32768 * 4);        // G x 256 i32
    float* R    = (float*)((char*)d_ws + (size_t)G * 32768 * 4 + (size_t)G * 256 * 4);  // G x 768 f32
    float* out  = (float*)d_out;

    // stage 1
    k_scatter<256, false><<<G * 4, 256, 0, stream>>>(x, src, dst, nullptr, A);
    k_gemm<256, true><<<512, 256, 0, stream>>>(x, A, Wr1, Wrel1, b1);
    k_pool<256, 128, 1><<<G, 256, 0, stream>>>(A, R, cmap, wp1);
    // stage 2
    k_scatter<128, true><<<G * 4, 256, 0, stream>>>(A, src, dst, cmap, A);
    k_gemm<128, false><<<256, 256, 0, stream>>>(A, A, Wr2, Wrel2, b2);
    k_pool<128, 64, 2><<<G, 256, 0, stream>>>(A, R, cmap, wp2);
    // stage 3
    k_scatter<64, true><<<G * 4, 256, 0, stream>>>(A, src, dst, cmap, A);
    k_gemm<64, false><<<128, 256, 0, stream>>>(A, A, Wr3, Wrel3, b3);
    k_pool<64, 32, 3><<<G, 256, 0, stream>>>(A, R, cmap, wp3);
    // head
    k_mlp<<<G, 128, 0, stream>>>(R, L1w, L1b, L2w, L2b, L3w, L3b, out);
}

// Round 3
// 399.996 us; speedup vs baseline: 4.0824x; 3.0837x over previous
//
#include <hip/hip_runtime.h>
#include <cstdint>
#include <cstddef>

#define G 256
#define EPER 4096
#define F 128

__device__ inline void lds_atomic_add(float* p, float v) {
    __hip_atomic_fetch_add(p, v, __ATOMIC_RELAXED, __HIP_MEMORY_SCOPE_WORKGROUP);
}

__device__ inline void fma4(float4& a, float s, const float4& w) {
    a.x = fmaf(s, w.x, a.x);
    a.y = fmaf(s, w.y, a.y);
    a.z = fmaf(s, w.z, a.z);
    a.w = fmaf(s, w.w, a.w);
}

// -------------------- aggregation via dense adjacency GEMM --------------------
// agg[d] = sum_s count(s->d) * x[s].  Adj built in LDS with ONE atomic per edge
// (vs one per edge*feature before: LDS f32 atomics measured ~3.2 cyc/lane/CU).
// Adj row m stores element (m,k) at column ((k+m) & (NS-1)) so the k-tile
// transpose read hits 32 distinct banks.
// BM dst rows per block; stage1 (NS=256) splits a graph into 2 dst-halves.
template<int NS, int BM, bool USE_MAP>
__global__ __launch_bounds__(256) void k_agg(const float* __restrict__ X,
                                             const int* __restrict__ src,
                                             const int* __restrict__ dst,
                                             const int* __restrict__ cmap,
                                             float* __restrict__ A) {
    constexpr bool SPLIT = (NS > BM);
    constexpr int RPT = BM / 16;  // rows per thread: 8 (BM=128) or 4 (BM=64)
    __shared__ float adjh[BM * NS];
    __shared__ float AsT[16 * BM];
    __shared__ float xs[16 * 128];
    __shared__ int smap[256];
    const int b = blockIdx.x, t = threadIdx.x;
    const int g = SPLIT ? (b >> 1) : b;
    const int mbase = SPLIT ? (b & 1) * BM : 0;

    float4* z4 = (float4*)adjh;
    #pragma unroll
    for (int i = t; i < BM * NS / 4; i += 256) z4[i] = float4{0.f, 0.f, 0.f, 0.f};
    if (USE_MAP) smap[t] = cmap[g * 256 + t];
    __syncthreads();

    // build counts: one LDS atomic per (live, in-half) edge
    const int* sg = src + (size_t)g * EPER;
    const int* dg = dst + (size_t)g * EPER;
    #pragma unroll 4
    for (int j = 0; j < 16; ++j) {
        int e = j * 256 + t;
        int s = sg[e], d = dg[e];
        if (USE_MAP) { s = smap[s]; d = smap[d]; }
        int m = d - mbase;
        if (s >= 0 && (unsigned)m < (unsigned)BM)
            lds_atomic_add(&adjh[m * NS + ((s + m) & (NS - 1))], 1.0f);
    }

    // x source rows: stage1 = input x; stages 2/3 = pooled rows (offset 128)
    const float* xgbase = USE_MAP ? (A + (size_t)g * 32768 + 16384)
                                  : (X + (size_t)g * 32768);

    float4 acc[RPT][2];
    #pragma unroll
    for (int i = 0; i < RPT; ++i) {
        acc[i][0] = float4{0.f, 0.f, 0.f, 0.f};
        acc[i][1] = float4{0.f, 0.f, 0.f, 0.f};
    }
    const int co = t & 15, rg = t >> 4;
    const int m_tr = (t >> 1) & (BM - 1), kb_tr = (t & 1) * 8;
    const int krow_st = t >> 4, f8_st = (t & 15) * 8;

    for (int k0 = 0; k0 < NS; k0 += 16) {
        __syncthreads();
        // transpose k-tile: AsT[kk][m] <- adjh[m][k0+kk] (rotated layout, 2 lanes/bank)
        #pragma unroll
        for (int q = 0; q < 8; ++q) {
            int kk = kb_tr + q;
            AsT[kk * BM + m_tr] = adjh[m_tr * NS + ((k0 + kk + m_tr) & (NS - 1))];
        }
        // stage x rows k0..k0+15
        {
            const float* xr = xgbase + (size_t)(k0 + krow_st) * F + f8_st;
            *(float4*)&xs[krow_st * F + f8_st] = *(const float4*)xr;
            *(float4*)&xs[krow_st * F + f8_st + 4] = *(const float4*)(xr + 4);
        }
        __syncthreads();

        const float4* A4 = (const float4*)AsT;
        const float4* X4 = (const float4*)xs;
        #pragma unroll
        for (int k = 0; k < 16; ++k) {
            float4 wa = X4[k * 32 + co * 2];
            float4 wb = X4[k * 32 + co * 2 + 1];
            if (RPT == 8) {
                float4 xa = A4[k * (BM / 4) + rg * 2];
                float4 xb = A4[k * (BM / 4) + rg * 2 + 1];
                fma4(acc[0][0], xa.x, wa); fma4(acc[0][1], xa.x, wb);
                fma4(acc[1][0], xa.y, wa); fma4(acc[1][1], xa.y, wb);
                fma4(acc[2][0], xa.z, wa); fma4(acc[2][1], xa.z, wb);
                fma4(acc[3][0], xa.w, wa); fma4(acc[3][1], xa.w, wb);
                fma4(acc[4][0], xb.x, wa); fma4(acc[4][1], xb.x, wb);
                fma4(acc[5][0], xb.y, wa); fma4(acc[5][1], xb.y, wb);
                fma4(acc[6][0], xb.z, wa); fma4(acc[6][1], xb.z, wb);
                fma4(acc[7][0], xb.w, wa); fma4(acc[7][1], xb.w, wb);
            } else {
                float4 xa = A4[k * (BM / 4) + rg];
                fma4(acc[0][0], xa.x, wa); fma4(acc[0][1], xa.x, wb);
                fma4(acc[1][0], xa.y, wa); fma4(acc[1][1], xa.y, wb);
                fma4(acc[2][0], xa.z, wa); fma4(acc[2][1], xa.z, wb);
                fma4(acc[3][0], xa.w, wa); fma4(acc[3][1], xa.w, wb);
            }
        }
    }

    #pragma unroll
    for (int i = 0; i < RPT; ++i) {
        int row = mbase + rg * RPT + i;
        float* orow = A + (size_t)g * 32768 + (size_t)row * F + co * 8;
        *(float4*)orow = acc[i][0];
        *(float4*)(orow + 4) = acc[i][1];
    }
}

// -------------------- conv GEMM: A[m,:] = relu(X[m]@Wr + AGG[m]@Wl + b) --------------------
// Treated as one GEMM, K=256 ([X | AGG] rows, [Wr; Wl] weights). BM=128, BN=128.
template<int NS, bool FIRST>
__global__ __launch_bounds__(256) void k_gemm(const float* __restrict__ X,
                                              float* __restrict__ A,
                                              const float* __restrict__ Wr,
                                              const float* __restrict__ Wl,
                                              const float* __restrict__ bias) {
    constexpr int L2NS = (NS == 256) ? 8 : (NS == 128) ? 7 : 6;
    __shared__ float AsT[32 * 128];  // [k][row] transposed A tile
    __shared__ float Ws[32 * 128];   // [k][col] W tile
    const int t = threadIdx.x;
    const int m0 = blockIdx.x * 128;
    const int co = t & 15, rg = t >> 4;  // 16 col-octs x 16 row-groups

    float4 acc[8][2];
    #pragma unroll
    for (int i = 0; i < 8; ++i) {
        acc[i][0] = float4{0.f, 0.f, 0.f, 0.f};
        acc[i][1] = float4{0.f, 0.f, 0.f, 0.f};
    }

    // A-staging: thread t loads row r_st = t>>1, k-quad set (t&1)*16 + q*4
    const int r_st = t >> 1;
    const int m_st = m0 + r_st;
    const int g_st = m_st >> L2NS, n_st = m_st & (NS - 1);
    const float* xrow = FIRST ? (X + (size_t)m_st * F)
                              : (X + (size_t)g_st * 32768 + (size_t)(128 + n_st) * F);
    const float* arow = A + (size_t)g_st * 32768 + (size_t)n_st * F;
    const int kq_base = (t & 1) * 16;

    for (int kt = 0; kt < 8; ++kt) {
        __syncthreads();
        // --- stage A tile (transposed) ---
        const float* srow = (kt < 4) ? (xrow + kt * 32) : (arow + (kt - 4) * 32);
        #pragma unroll
        for (int q = 0; q < 4; ++q) {
            float4 v = *(const float4*)(srow + kq_base + q * 4);
            int kl = kq_base + q * 4;
            AsT[(kl + 0) * 128 + r_st] = v.x;
            AsT[(kl + 1) * 128 + r_st] = v.y;
            AsT[(kl + 2) * 128 + r_st] = v.z;
            AsT[(kl + 3) * 128 + r_st] = v.w;
        }
        // --- stage W tile ---
        const float* wsrc = (kt < 4) ? (Wr + (size_t)kt * 32 * F) : (Wl + (size_t)(kt - 4) * 32 * F);
        {
            const int fu = t & 31;
            #pragma unroll
            for (int q = 0; q < 4; ++q) {
                int k = q * 8 + (t >> 5);
                *(float4*)(Ws + k * 128 + fu * 4) = *(const float4*)(wsrc + (size_t)k * F + fu * 4);
            }
        }
        __syncthreads();

        const float4* AsT4 = (const float4*)AsT;
        const float4* Ws4 = (const float4*)Ws;
        #pragma unroll 4
        for (int k = 0; k < 32; ++k) {
            float4 xa = AsT4[k * 32 + rg * 2];
            float4 xb = AsT4[k * 32 + rg * 2 + 1];
            float4 wa = Ws4[k * 32 + co * 2];
            float4 wb = Ws4[k * 32 + co * 2 + 1];
            fma4(acc[0][0], xa.x, wa); fma4(acc[0][1], xa.x, wb);
            fma4(acc[1][0], xa.y, wa); fma4(acc[1][1], xa.y, wb);
            fma4(acc[2][0], xa.z, wa); fma4(acc[2][1], xa.z, wb);
            fma4(acc[3][0], xa.w, wa); fma4(acc[3][1], xa.w, wb);
            fma4(acc[4][0], xb.x, wa); fma4(acc[4][1], xb.x, wb);
            fma4(acc[5][0], xb.y, wa); fma4(acc[5][1], xb.y, wb);
            fma4(acc[6][0], xb.z, wa); fma4(acc[6][1], xb.z, wb);
            fma4(acc[7][0], xb.w, wa); fma4(acc[7][1], xb.w, wb);
        }
    }

    float4 b0 = *(const float4*)(bias + co * 8);
    float4 b1 = *(const float4*)(bias + co * 8 + 4);
    #pragma unroll
    for (int i = 0; i < 8; ++i) {
        int m = m0 + rg * 8 + i;
        int gg = m >> L2NS, nn = m & (NS - 1);
        float* orow = A + (size_t)gg * 32768 + (size_t)nn * F + co * 8;
        float4 o0, o1;
        o0.x = fmaxf(acc[i][0].x + b0.x, 0.f);
        o0.y = fmaxf(acc[i][0].y + b0.y, 0.f);
        o0.z = fmaxf(acc[i][0].z + b0.z, 0.f);
        o0.w = fmaxf(acc[i][0].w + b0.w, 0.f);
        o1.x = fmaxf(acc[i][1].x + b1.x, 0.f);
        o1.y = fmaxf(acc[i][1].y + b1.y, 0.f);
        o1.z = fmaxf(acc[i][1].z + b1.z, 0.f);
        o1.w = fmaxf(acc[i][1].w + b1.w, 0.f);
        *(float4*)orow = o0;
        *(float4*)(orow + 4) = o1;
    }
}

// -------------------- top-k pool + readout + cmap update --------------------
template<int N, int K, int STAGE>
__global__ __launch_bounds__(256) void k_pool(float* __restrict__ A,
                                              float* __restrict__ R,
                                              int* __restrict__ cmap,
                                              const float* __restrict__ wp) {
    __shared__ float sc[256];
    __shared__ unsigned long long keys[256];
    __shared__ float hp[K * F];
    __shared__ int sel[K];
    __shared__ int inv[N];
    __shared__ float wn[F];
    __shared__ float snorm_s;
    const int g = blockIdx.x, t = threadIdx.x;
    const float* h = A + (size_t)g * 32768;

    if (t < 64) {
        float v = wp[t] * wp[t] + wp[t + 64] * wp[t + 64];
        #pragma unroll
        for (int o = 32; o; o >>= 1) v += __shfl_xor(v, o);
        if (t == 0) snorm_s = sqrtf(v);
    }
    __syncthreads();
    if (t < 128) wn[t] = wp[t] / snorm_s;
    __syncthreads();

    // scores: one wave per node row
    const int wid = t >> 6, lane = t & 63;
    for (int n = wid; n < N; n += 4) {
        float p = h[n * F + lane] * wn[lane] + h[n * F + 64 + lane] * wn[64 + lane];
        #pragma unroll
        for (int o = 32; o; o >>= 1) p += __shfl_xor(p, o);
        if (lane == 0) sc[n] = p;
    }
    __syncthreads();

    // sort keys descending: (order-preserving score bits, ties -> smaller idx first)
    if (t < N) {
        unsigned u = __float_as_uint(sc[t]);
        u = (u & 0x80000000u) ? ~u : (u | 0x80000000u);
        keys[t] = ((unsigned long long)u << 32) | (unsigned)(~t);
    } else {
        keys[t] = 0ull;
    }
    __syncthreads();
    for (int kk = 2; kk <= 256; kk <<= 1) {
        for (int j = kk >> 1; j > 0; j >>= 1) {
            int ixj = t ^ j;
            if (ixj > t) {
                unsigned long long a = keys[t], b = keys[ixj];
                bool up = (t & kk) == 0;
                if (up ? (a < b) : (a > b)) { keys[t] = b; keys[ixj] = a; }
            }
            __syncthreads();
        }
    }

    if (t < K) sel[t] = (int)(~(unsigned)keys[t]);
    if (t < N) inv[t] = -1;
    __syncthreads();
    if (t < K) inv[sel[t]] = t;
    __syncthreads();

    // composed original-node -> current-stage-id map
    {
        int c = (STAGE == 1) ? t : cmap[g * 256 + t];
        cmap[g * 256 + t] = (c >= 0) ? inv[c] : -1;
    }

    // gather gated rows into LDS (all reads of h complete before any global write)
    const int f = t & 127;
    for (int j = t >> 7; j < K; j += 2) {
        int n = sel[j];
        float gate = tanhf(sc[n]);
        hp[j * F + f] = h[n * F + f] * gate;
    }
    __syncthreads();

    if (STAGE < 3) {
        for (int j = t >> 7; j < K; j += 2)
            A[(size_t)g * 32768 + (size_t)(128 + j) * F + f] = hp[j * F + f];
    }

    // readout: max & mean over pooled nodes
    if (t < 128) {
        float mx = -INFINITY, sm = 0.f;
        for (int j = 0; j < K; ++j) {
            float v = hp[j * F + t];
            mx = fmaxf(mx, v);
            sm += v;
        }
        R[(size_t)g * 768 + (STAGE - 1) * 256 + t] = mx;
        R[(size_t)g * 768 + (STAGE - 1) * 256 + 128 + t] = sm * (1.0f / K);
    }
}

// -------------------- final MLP + log_softmax --------------------
__global__ __launch_bounds__(128) void k_mlp(const float* __restrict__ R,
                                             const float* __restrict__ W1, const float* __restrict__ b1,
                                             const float* __restrict__ W2, const float* __restrict__ b2,
                                             const float* __restrict__ W3, const float* __restrict__ b3,
                                             float* __restrict__ out) {
    __shared__ float z[768];
    __shared__ float z2[128];
    __shared__ float z3[64];
    __shared__ float lg[10];
    __shared__ float lse;
    const int g = blockIdx.x, t = threadIdx.x;

    #pragma unroll
    for (int i = 0; i < 6; ++i) z[t + i * 128] = R[(size_t)g * 768 + t + i * 128];
    __syncthreads();

    float acc = b1[t];
    #pragma unroll 8
    for (int k = 0; k < 768; ++k) acc = fmaf(z[k], W1[k * 128 + t], acc);
    z2[t] = fmaxf(acc, 0.f);
    __syncthreads();

    if (t < 64) {
        float a2 = b2[t];
        #pragma unroll 8
        for (int k = 0; k < 128; ++k) a2 = fmaf(z2[k], W2[k * 64 + t], a2);
        z3[t] = fmaxf(a2, 0.f);
    }
    __syncthreads();

    if (t < 10) {
        float a3 = b3[t];
        #pragma unroll 8
        for (int k = 0; k < 64; ++k) a3 = fmaf(z3[k], W3[k * 10 + t], a3);
        lg[t] = a3;
    }
    __syncthreads();

    if (t == 0) {
        float m = lg[0];
        for (int c = 1; c < 10; ++c) m = fmaxf(m, lg[c]);
        float s = 0.f;
        for (int c = 0; c < 10; ++c) s += expf(lg[c] - m);
        lse = m + logf(s);
    }
    __syncthreads();
    if (t < 10) out[(size_t)g * 10 + t] = lg[t] - lse;
}

extern "C" void kernel_launch(void* const* d_in, const int* in_sizes, int n_in,
                              void* d_out, int out_size, void* d_ws, size_t ws_size,
                              hipStream_t stream) {
    (void)in_sizes; (void)n_in; (void)out_size; (void)ws_size;
    const float* x    = (const float*)d_in[0];
    const int*   src  = (const int*)d_in[1];
    const int*   dst  = (const int*)d_in[2];
    const float* Wr1  = (const float*)d_in[3];
    const float* Wrel1= (const float*)d_in[4];
    const float* b1   = (const float*)d_in[5];
    const float* wp1  = (const float*)d_in[6];
    const float* Wr2  = (const float*)d_in[7];
    const float* Wrel2= (const float*)d_in[8];
    const float* b2   = (const float*)d_in[9];
    const float* wp2  = (const float*)d_in[10];
    const float* Wr3  = (const float*)d_in[11];
    const float* Wrel3= (const float*)d_in[12];
    const float* b3   = (const float*)d_in[13];
    const float* wp3  = (const float*)d_in[14];
    const float* L1w  = (const float*)d_in[15];
    const float* L1b  = (const float*)d_in[16];
    const float* L2w  = (const float*)d_in[17];
    const float* L2b  = (const float*)d_in[18];
    const float* L3w  = (const float*)d_in[19];
    const float* L3b  = (const float*)d_in[20];

    float* A    = (float*)d_ws;                                       // G x 256 x 128 f32 (33.5 MB)
    int*   cmap = (int*)((char*)d_ws + (size_t)G * 32768 * 4);        // G x 256 i32
    float* R    = (float*)((char*)d_ws + (size_t)G * 32768 * 4 + (size_t)G * 256 * 4);  // G x 768 f32
    float* out  = (float*)d_out;

    // stage 1
    k_agg<256, 128, false><<<G * 2, 256, 0, stream>>>(x, src, dst, nullptr, A);
    k_gemm<256, true><<<512, 256, 0, stream>>>(x, A, Wr1, Wrel1, b1);
    k_pool<256, 128, 1><<<G, 256, 0, stream>>>(A, R, cmap, wp1);
    // stage 2
    k_agg<128, 128, true><<<G, 256, 0, stream>>>(x, src, dst, cmap, A);
    k_gemm<128, false><<<256, 256, 0, stream>>>(A, A, Wr2, Wrel2, b2);
    k_pool<128, 64, 2><<<G, 256, 0, stream>>>(A, R, cmap, wp2);
    // stage 3
    k_agg<64, 64, true><<<G, 256, 0, stream>>>(x, src, dst, cmap, A);
    k_gemm<64, false><<<128, 256, 0, stream>>>(A, A, Wr3, Wrel3, b3);
    k_pool<64, 32, 3><<<G, 256, 0, stream>>>(A, R, cmap, wp3);
    // head
    k_mlp<<<G, 128, 0, stream>>>(R, L1w, L1b, L2w, L2b, L3w, L3b, out);
}

// Round 4
// 334.062 us; speedup vs baseline: 4.8881x; 1.1974x over previous
//
#include <hip/hip_runtime.h>
#include <cstdint>
#include <cstddef>

#define G 256
#define EPER 4096
#define F 128

typedef __attribute__((ext_vector_type(8))) short short8;
typedef __attribute__((ext_vector_type(4))) float f32x4;

__device__ inline unsigned short f2bf(float f) {
    unsigned u = __float_as_uint(f);
    u += 0x7FFFu + ((u >> 16) & 1u);
    return (unsigned short)(u >> 16);
}
__device__ inline float bf2f(unsigned short b) { return __uint_as_float(((unsigned)b) << 16); }

__device__ inline void fma4(float4& a, float s, const float4& w) {
    a.x = fmaf(s, w.x, a.x);
    a.y = fmaf(s, w.y, a.y);
    a.z = fmaf(s, w.z, a.z);
    a.w = fmaf(s, w.w, a.w);
}

// -------------------- aggregation: agg = Adj @ x on MFMA --------------------
// Adj counts exact in bf16 (small ints); x split 3-way into bf16 (b1+b2+b3,
// residual ~2^-24 rel) -> fp32-grade result on the 2.4 PF bf16 matrix pipe.
// Adj built as packed u8 in LDS (1 atomic/edge), rows rotated by 4m bytes so
// tile-conversion u32 reads spread banks. Fragment tiles stored [koct][row][8k]
// so all MFMA-feeding reads are b128 at the bank floor.
template<int NS, int BM, bool USE_MAP>
__global__ __launch_bounds__(256) void k_agg(const float* __restrict__ X,
                                             const int* __restrict__ src,
                                             const int* __restrict__ dst,
                                             const int* __restrict__ cmap,
                                             float* __restrict__ A) {
    constexpr bool SPLIT = (NS > BM);
    constexpr int RW = BM / 4;   // rows per wave
    constexpr int MT = RW / 16;  // 16-row MFMA tiles per wave
    constexpr int NS4 = NS / 4;
    __shared__ unsigned adjc[BM * NS4];  // packed u8 counts, row m rotated by 4m bytes
    __shared__ short adjT[4 * BM * 8];   // [koct][m][8k] bf16 tile for current K-step
    __shared__ short xs[3][4 * 128 * 8]; // 3-way split, [koct][n][8k]
    __shared__ int smap[256];

    const int b = blockIdx.x, t = threadIdx.x;
    const int g = SPLIT ? (b >> 1) : b;
    const int mbase = SPLIT ? (b & 1) * BM : 0;

    {
        uint4* z = (uint4*)adjc;
        #pragma unroll
        for (int i = t; i < BM * NS4 / 4; i += 256) z[i] = uint4{0, 0, 0, 0};
    }
    if (USE_MAP) smap[t] = cmap[g * 256 + t];
    __syncthreads();

    // build counts: one u32 atomic per live edge
    const int* sg = src + (size_t)g * EPER;
    const int* dg = dst + (size_t)g * EPER;
    #pragma unroll 4
    for (int j = 0; j < 16; ++j) {
        int e = j * 256 + t;
        int s = sg[e], d = dg[e];
        if (USE_MAP) { s = smap[s]; d = smap[d]; }
        int m = d - mbase;
        if (s >= 0 && (unsigned)m < (unsigned)BM) {
            int pos = (s + 4 * m) & (NS - 1);
            __hip_atomic_fetch_add(&adjc[m * NS4 + (pos >> 2)], 1u << ((pos & 3) * 8),
                                   __ATOMIC_RELAXED, __HIP_MEMORY_SCOPE_WORKGROUP);
        }
    }

    const float* xsrc = USE_MAP ? (A + (size_t)g * 32768 + 16384) : (X + (size_t)g * 32768);

    f32x4 acc[MT][8];
    #pragma unroll
    for (int i = 0; i < MT; ++i)
        #pragma unroll
        for (int c = 0; c < 8; ++c) acc[i][c] = f32x4{0.f, 0.f, 0.f, 0.f};

    const int lane = t & 63, wv = t >> 6;
    constexpr int TPR = 256 / BM;       // threads per adj row (2 or 4)
    constexpr int CPT = 32 / TPR;       // k-cells per thread (16 or 8)
    const int mA = t / TPR, kgA = (t % TPR) * CPT;
    const int nX = t & 127, kgX = (t >> 7) * 16;

    for (int k0 = 0; k0 < NS; k0 += 32) {
        __syncthreads();
        // --- convert adj u8 tile -> bf16 [koct][m][8k] ---
        {
            unsigned short cs[CPT];
            #pragma unroll
            for (int q = 0; q < CPT / 4; ++q) {
                unsigned w = adjc[mA * NS4 + ((((k0 + kgA) >> 2) + mA + q) & (NS4 - 1))];
                cs[q * 4 + 0] = f2bf((float)(w & 255u));
                cs[q * 4 + 1] = f2bf((float)((w >> 8) & 255u));
                cs[q * 4 + 2] = f2bf((float)((w >> 16) & 255u));
                cs[q * 4 + 3] = f2bf((float)(w >> 24));
            }
            #pragma unroll
            for (int c = 0; c < CPT / 8; ++c) {
                short8 w8;
                #pragma unroll
                for (int j = 0; j < 8; ++j) w8[j] = (short)cs[c * 8 + j];
                *(short8*)&adjT[((kgA >> 3) + c) * BM * 8 + mA * 8] = w8;
            }
        }
        // --- stage x rows k0..k0+31 (coalesced global, 3-way bf16 split) ---
        {
            float v[16];
            #pragma unroll
            for (int i = 0; i < 16; ++i)
                v[i] = xsrc[(size_t)(k0 + kgX + i) * F + nX];
            #pragma unroll
            for (int c = 0; c < 2; ++c) {
                short8 h1, h2, h3;
                #pragma unroll
                for (int j = 0; j < 8; ++j) {
                    float f = v[c * 8 + j];
                    unsigned short a1 = f2bf(f);
                    float r = f - bf2f(a1);
                    unsigned short a2 = f2bf(r);
                    float r2 = r - bf2f(a2);
                    h1[j] = (short)a1; h2[j] = (short)a2; h3[j] = (short)f2bf(r2);
                }
                int ko = (kgX >> 3) + c;
                *(short8*)&xs[0][ko * 1024 + nX * 8] = h1;
                *(short8*)&xs[1][ko * 1024 + nX * 8] = h2;
                *(short8*)&xs[2][ko * 1024 + nX * 8] = h3;
            }
        }
        __syncthreads();
        // --- MFMA: acc += AdjTile @ xsplit ---
        short8 afr[MT];
        #pragma unroll
        for (int mt = 0; mt < MT; ++mt)
            afr[mt] = *(const short8*)&adjT[(lane >> 4) * BM * 8 + (wv * RW + mt * 16 + (lane & 15)) * 8];
        #pragma unroll
        for (int s = 0; s < 3; ++s) {
            #pragma unroll
            for (int ct = 0; ct < 8; ++ct) {
                short8 bfr = *(const short8*)&xs[s][(lane >> 4) * 1024 + (ct * 16 + (lane & 15)) * 8];
                #pragma unroll
                for (int mt = 0; mt < MT; ++mt)
                    acc[mt][ct] = __builtin_amdgcn_mfma_f32_16x16x32_bf16(afr[mt], bfr, acc[mt][ct], 0, 0, 0);
            }
        }
    }

    // write agg rows (D: col=lane&15, row=(lane>>4)*4+reg)
    float* Ag = A + (size_t)g * 32768;
    #pragma unroll
    for (int mt = 0; mt < MT; ++mt) {
        int r0 = mbase + wv * RW + mt * 16 + (lane >> 4) * 4;
        #pragma unroll
        for (int ct = 0; ct < 8; ++ct) {
            int col = ct * 16 + (lane & 15);
            #pragma unroll
            for (int r = 0; r < 4; ++r)
                Ag[(size_t)(r0 + r) * F + col] = acc[mt][ct][r];
        }
    }
}

// -------------------- conv GEMM: A[m,:] = relu(X[m]@Wr + AGG[m]@Wl + b) --------------------
template<int NS, bool FIRST>
__global__ __launch_bounds__(256) void k_gemm(const float* __restrict__ X,
                                              float* __restrict__ A,
                                              const float* __restrict__ Wr,
                                              const float* __restrict__ Wl,
                                              const float* __restrict__ bias) {
    constexpr int L2NS = (NS == 256) ? 8 : (NS == 128) ? 7 : 6;
    __shared__ float AsT[32 * 128];  // [k][row] transposed A tile
    __shared__ float Ws[32 * 128];   // [k][col] W tile
    const int t = threadIdx.x;
    const int m0 = blockIdx.x * 128;
    const int co = t & 15, rg = t >> 4;

    float4 acc[8][2];
    #pragma unroll
    for (int i = 0; i < 8; ++i) {
        acc[i][0] = float4{0.f, 0.f, 0.f, 0.f};
        acc[i][1] = float4{0.f, 0.f, 0.f, 0.f};
    }

    const int r_st = t >> 1;
    const int m_st = m0 + r_st;
    const int g_st = m_st >> L2NS, n_st = m_st & (NS - 1);
    const float* xrow = FIRST ? (X + (size_t)m_st * F)
                              : (X + (size_t)g_st * 32768 + (size_t)(128 + n_st) * F);
    const float* arow = A + (size_t)g_st * 32768 + (size_t)n_st * F;
    const int kq_base = (t & 1) * 16;

    for (int kt = 0; kt < 8; ++kt) {
        __syncthreads();
        const float* srow = (kt < 4) ? (xrow + kt * 32) : (arow + (kt - 4) * 32);
        #pragma unroll
        for (int q = 0; q < 4; ++q) {
            float4 v = *(const float4*)(srow + kq_base + q * 4);
            int kl = kq_base + q * 4;
            AsT[(kl + 0) * 128 + r_st] = v.x;
            AsT[(kl + 1) * 128 + r_st] = v.y;
            AsT[(kl + 2) * 128 + r_st] = v.z;
            AsT[(kl + 3) * 128 + r_st] = v.w;
        }
        const float* wsrc = (kt < 4) ? (Wr + (size_t)kt * 32 * F) : (Wl + (size_t)(kt - 4) * 32 * F);
        {
            const int fu = t & 31;
            #pragma unroll
            for (int q = 0; q < 4; ++q) {
                int k = q * 8 + (t >> 5);
                *(float4*)(Ws + k * 128 + fu * 4) = *(const float4*)(wsrc + (size_t)k * F + fu * 4);
            }
        }
        __syncthreads();

        const float4* AsT4 = (const float4*)AsT;
        const float4* Ws4 = (const float4*)Ws;
        #pragma unroll 4
        for (int k = 0; k < 32; ++k) {
            float4 xa = AsT4[k * 32 + rg * 2];
            float4 xb = AsT4[k * 32 + rg * 2 + 1];
            float4 wa = Ws4[k * 32 + co * 2];
            float4 wb = Ws4[k * 32 + co * 2 + 1];
            fma4(acc[0][0], xa.x, wa); fma4(acc[0][1], xa.x, wb);
            fma4(acc[1][0], xa.y, wa); fma4(acc[1][1], xa.y, wb);
            fma4(acc[2][0], xa.z, wa); fma4(acc[2][1], xa.z, wb);
            fma4(acc[3][0], xa.w, wa); fma4(acc[3][1], xa.w, wb);
            fma4(acc[4][0], xb.x, wa); fma4(acc[4][1], xb.x, wb);
            fma4(acc[5][0], xb.y, wa); fma4(acc[5][1], xb.y, wb);
            fma4(acc[6][0], xb.z, wa); fma4(acc[6][1], xb.z, wb);
            fma4(acc[7][0], xb.w, wa); fma4(acc[7][1], xb.w, wb);
        }
    }

    float4 b0 = *(const float4*)(bias + co * 8);
    float4 b1 = *(const float4*)(bias + co * 8 + 4);
    #pragma unroll
    for (int i = 0; i < 8; ++i) {
        int m = m0 + rg * 8 + i;
        int gg = m >> L2NS, nn = m & (NS - 1);
        float* orow = A + (size_t)gg * 32768 + (size_t)nn * F + co * 8;
        float4 o0, o1;
        o0.x = fmaxf(acc[i][0].x + b0.x, 0.f);
        o0.y = fmaxf(acc[i][0].y + b0.y, 0.f);
        o0.z = fmaxf(acc[i][0].z + b0.z, 0.f);
        o0.w = fmaxf(acc[i][0].w + b0.w, 0.f);
        o1.x = fmaxf(acc[i][1].x + b1.x, 0.f);
        o1.y = fmaxf(acc[i][1].y + b1.y, 0.f);
        o1.z = fmaxf(acc[i][1].z + b1.z, 0.f);
        o1.w = fmaxf(acc[i][1].w + b1.w, 0.f);
        *(float4*)orow = o0;
        *(float4*)(orow + 4) = o1;
    }
}

// -------------------- top-k pool + readout + cmap update --------------------
template<int N, int K, int STAGE>
__global__ __launch_bounds__(256) void k_pool(float* __restrict__ A,
                                              float* __restrict__ R,
                                              int* __restrict__ cmap,
                                              const float* __restrict__ wp) {
    __shared__ float sc[256];
    __shared__ unsigned long long keys[256];
    __shared__ float hp[K * F];
    __shared__ int sel[K];
    __shared__ int inv[N];
    __shared__ float wn[F];
    __shared__ float snorm_s;
    const int g = blockIdx.x, t = threadIdx.x;
    const float* h = A + (size_t)g * 32768;

    if (t < 64) {
        float v = wp[t] * wp[t] + wp[t + 64] * wp[t + 64];
        #pragma unroll
        for (int o = 32; o; o >>= 1) v += __shfl_xor(v, o);
        if (t == 0) snorm_s = sqrtf(v);
    }
    __syncthreads();
    if (t < 128) wn[t] = wp[t] / snorm_s;
    __syncthreads();

    const int wid = t >> 6, lane = t & 63;
    for (int n = wid; n < N; n += 4) {
        float p = h[n * F + lane] * wn[lane] + h[n * F + 64 + lane] * wn[64 + lane];
        #pragma unroll
        for (int o = 32; o; o >>= 1) p += __shfl_xor(p, o);
        if (lane == 0) sc[n] = p;
    }
    __syncthreads();

    if (t < N) {
        unsigned u = __float_as_uint(sc[t]);
        u = (u & 0x80000000u) ? ~u : (u | 0x80000000u);
        keys[t] = ((unsigned long long)u << 32) | (unsigned)(~t);
    } else {
        keys[t] = 0ull;
    }
    __syncthreads();
    for (int kk = 2; kk <= 256; kk <<= 1) {
        for (int j = kk >> 1; j > 0; j >>= 1) {
            int ixj = t ^ j;
            if (ixj > t) {
                unsigned long long a = keys[t], b = keys[ixj];
                bool up = (t & kk) == 0;
                if (up ? (a < b) : (a > b)) { keys[t] = b; keys[ixj] = a; }
            }
            __syncthreads();
        }
    }

    if (t < K) sel[t] = (int)(~(unsigned)keys[t]);
    if (t < N) inv[t] = -1;
    __syncthreads();
    if (t < K) inv[sel[t]] = t;
    __syncthreads();

    {
        int c = (STAGE == 1) ? t : cmap[g * 256 + t];
        cmap[g * 256 + t] = (c >= 0) ? inv[c] : -1;
    }

    const int f = t & 127;
    for (int j = t >> 7; j < K; j += 2) {
        int n = sel[j];
        float gate = tanhf(sc[n]);
        hp[j * F + f] = h[n * F + f] * gate;
    }
    __syncthreads();

    if (STAGE < 3) {
        for (int j = t >> 7; j < K; j += 2)
            A[(size_t)g * 32768 + (size_t)(128 + j) * F + f] = hp[j * F + f];
    }

    if (t < 128) {
        float mx = -INFINITY, sm = 0.f;
        for (int j = 0; j < K; ++j) {
            float v = hp[j * F + t];
            mx = fmaxf(mx, v);
            sm += v;
        }
        R[(size_t)g * 768 + (STAGE - 1) * 256 + t] = mx;
        R[(size_t)g * 768 + (STAGE - 1) * 256 + 128 + t] = sm * (1.0f / K);
    }
}

// -------------------- final MLP + log_softmax --------------------
__global__ __launch_bounds__(128) void k_mlp(const float* __restrict__ R,
                                             const float* __restrict__ W1, const float* __restrict__ b1,
                                             const float* __restrict__ W2, const float* __restrict__ b2,
                                             const float* __restrict__ W3, const float* __restrict__ b3,
                                             float* __restrict__ out) {
    __shared__ float z[768];
    __shared__ float z2[128];
    __shared__ float z3[64];
    __shared__ float lg[10];
    __shared__ float lse;
    const int g = blockIdx.x, t = threadIdx.x;

    #pragma unroll
    for (int i = 0; i < 6; ++i) z[t + i * 128] = R[(size_t)g * 768 + t + i * 128];
    __syncthreads();

    float acc = b1[t];
    #pragma unroll 8
    for (int k = 0; k < 768; ++k) acc = fmaf(z[k], W1[k * 128 + t], acc);
    z2[t] = fmaxf(acc, 0.f);
    __syncthreads();

    if (t < 64) {
        float a2 = b2[t];
        #pragma unroll 8
        for (int k = 0; k < 128; ++k) a2 = fmaf(z2[k], W2[k * 64 + t], a2);
        z3[t] = fmaxf(a2, 0.f);
    }
    __syncthreads();

    if (t < 10) {
        float a3 = b3[t];
        #pragma unroll 8
        for (int k = 0; k < 64; ++k) a3 = fmaf(z3[k], W3[k * 10 + t], a3);
        lg[t] = a3;
    }
    __syncthreads();

    if (t == 0) {
        float m = lg[0];
        for (int c = 1; c < 10; ++c) m = fmaxf(m, lg[c]);
        float s = 0.f;
        for (int c = 0; c < 10; ++c) s += expf(lg[c] - m);
        lse = m + logf(s);
    }
    __syncthreads();
    if (t < 10) out[(size_t)g * 10 + t] = lg[t] - lse;
}

extern "C" void kernel_launch(void* const* d_in, const int* in_sizes, int n_in,
                              void* d_out, int out_size, void* d_ws, size_t ws_size,
                              hipStream_t stream) {
    (void)in_sizes; (void)n_in; (void)out_size; (void)ws_size;
    const float* x    = (const float*)d_in[0];
    const int*   src  = (const int*)d_in[1];
    const int*   dst  = (const int*)d_in[2];
    const float* Wr1  = (const float*)d_in[3];
    const float* Wrel1= (const float*)d_in[4];
    const float* b1   = (const float*)d_in[5];
    const float* wp1  = (const float*)d_in[6];
    const float* Wr2  = (const float*)d_in[7];
    const float* Wrel2= (const float*)d_in[8];
    const float* b2   = (const float*)d_in[9];
    const float* wp2  = (const float*)d_in[10];
    const float* Wr3  = (const float*)d_in[11];
    const float* Wrel3= (const float*)d_in[12];
    const float* b3   = (const float*)d_in[13];
    const float* wp3  = (const float*)d_in[14];
    const float* L1w  = (const float*)d_in[15];
    const float* L1b  = (const float*)d_in[16];
    const float* L2w  = (const float*)d_in[17];
    const float* L2b  = (const float*)d_in[18];
    const float* L3w  = (const float*)d_in[19];
    const float* L3b  = (const float*)d_in[20];

    float* A    = (float*)d_ws;                                       // G x 256 x 128 f32
    int*   cmap = (int*)((char*)d_ws + (size_t)G * 32768 * 4);        // G x 256 i32
    float* R    = (float*)((char*)d_ws + (size_t)G * 32768 * 4 + (size_t)G * 256 * 4);  // G x 768 f32
    float* out  = (float*)d_out;

    // stage 1
    k_agg<256, 128, false><<<G * 2, 256, 0, stream>>>(x, src, dst, nullptr, A);
    k_gemm<256, true><<<512, 256, 0, stream>>>(x, A, Wr1, Wrel1, b1);
    k_pool<256, 128, 1><<<G, 256, 0, stream>>>(A, R, cmap, wp1);
    // stage 2
    k_agg<128, 128, true><<<G, 256, 0, stream>>>(x, src, dst, cmap, A);
    k_gemm<128, false><<<256, 256, 0, stream>>>(A, A, Wr2, Wrel2, b2);
    k_pool<128, 64, 2><<<G, 256, 0, stream>>>(A, R, cmap, wp2);
    // stage 3
    k_agg<64, 64, true><<<G, 256, 0, stream>>>(x, src, dst, cmap, A);
    k_gemm<64, false><<<128, 256, 0, stream>>>(A, A, Wr3, Wrel3, b3);
    k_pool<64, 32, 3><<<G, 256, 0, stream>>>(A, R, cmap, wp3);
    // head
    k_mlp<<<G, 128, 0, stream>>>(R, L1w, L1b, L2w, L2b, L3w, L3b, out);
}

// Round 5
// 275.577 us; speedup vs baseline: 5.9256x; 1.2122x over previous
//
#include <hip/hip_runtime.h>
#include <cstdint>
#include <cstddef>

#define G 256
#define EPER 4096
#define F 128

typedef __attribute__((ext_vector_type(8))) short short8;
typedef __attribute__((ext_vector_type(4))) float f32x4;

__device__ inline unsigned short f2bf(float f) {
    unsigned u = __float_as_uint(f);
    u += 0x7FFFu + ((u >> 16) & 1u);
    return (unsigned short)(u >> 16);
}
__device__ inline float bf2f(unsigned short b) { return __uint_as_float(((unsigned)b) << 16); }

// -------------------- aggregation: agg = Adj @ x on MFMA --------------------
// Adj counts exact in bf16 (small ints); x split 3-way into bf16 (b1+b2+b3,
// residual ~2^-24 rel) -> fp32-grade result on the bf16 matrix pipe.
template<int NS, int BM, bool USE_MAP>
__global__ __launch_bounds__(256) void k_agg(const float* __restrict__ X,
                                             const int* __restrict__ src,
                                             const int* __restrict__ dst,
                                             const int* __restrict__ cmap,
                                             float* __restrict__ A) {
    constexpr bool SPLIT = (NS > BM);
    constexpr int RW = BM / 4;   // rows per wave
    constexpr int MT = RW / 16;  // 16-row MFMA tiles per wave
    constexpr int NS4 = NS / 4;
    __shared__ unsigned adjc[BM * NS4];  // packed u8 counts, row m rotated by 4m bytes
    __shared__ short adjT[4 * BM * 8];   // [koct][m][8k] bf16 tile for current K-step
    __shared__ short xs[3][4 * 128 * 8]; // 3-way split, [koct][n][8k]
    __shared__ int smap[256];

    const int b = blockIdx.x, t = threadIdx.x;
    const int g = SPLIT ? (b >> 1) : b;
    const int mbase = SPLIT ? (b & 1) * BM : 0;

    {
        uint4* z = (uint4*)adjc;
        #pragma unroll
        for (int i = t; i < BM * NS4 / 4; i += 256) z[i] = uint4{0, 0, 0, 0};
    }
    if (USE_MAP) smap[t] = cmap[g * 256 + t];
    __syncthreads();

    // build counts: one u32 atomic per live edge
    const int* sg = src + (size_t)g * EPER;
    const int* dg = dst + (size_t)g * EPER;
    #pragma unroll 4
    for (int j = 0; j < 16; ++j) {
        int e = j * 256 + t;
        int s = sg[e], d = dg[e];
        if (USE_MAP) { s = smap[s]; d = smap[d]; }
        int m = d - mbase;
        if (s >= 0 && (unsigned)m < (unsigned)BM) {
            int pos = (s + 4 * m) & (NS - 1);
            __hip_atomic_fetch_add(&adjc[m * NS4 + (pos >> 2)], 1u << ((pos & 3) * 8),
                                   __ATOMIC_RELAXED, __HIP_MEMORY_SCOPE_WORKGROUP);
        }
    }

    const float* xsrc = USE_MAP ? (A + (size_t)g * 32768 + 16384) : (X + (size_t)g * 32768);

    f32x4 acc[MT][8];
    #pragma unroll
    for (int i = 0; i < MT; ++i)
        #pragma unroll
        for (int c = 0; c < 8; ++c) acc[i][c] = f32x4{0.f, 0.f, 0.f, 0.f};

    const int lane = t & 63, wv = t >> 6;
    constexpr int TPR = 256 / BM;       // threads per adj row (2 or 4)
    constexpr int CPT = 32 / TPR;       // k-cells per thread (16 or 8)
    const int mA = t / TPR, kgA = (t % TPR) * CPT;
    const int nX = t & 127, kgX = (t >> 7) * 16;

    for (int k0 = 0; k0 < NS; k0 += 32) {
        __syncthreads();
        // --- convert adj u8 tile -> bf16 [koct][m][8k] ---
        {
            unsigned short cs[CPT];
            #pragma unroll
            for (int q = 0; q < CPT / 4; ++q) {
                unsigned w = adjc[mA * NS4 + ((((k0 + kgA) >> 2) + mA + q) & (NS4 - 1))];
                cs[q * 4 + 0] = f2bf((float)(w & 255u));
                cs[q * 4 + 1] = f2bf((float)((w >> 8) & 255u));
                cs[q * 4 + 2] = f2bf((float)((w >> 16) & 255u));
                cs[q * 4 + 3] = f2bf((float)(w >> 24));
            }
            #pragma unroll
            for (int c = 0; c < CPT / 8; ++c) {
                short8 w8;
                #pragma unroll
                for (int j = 0; j < 8; ++j) w8[j] = (short)cs[c * 8 + j];
                *(short8*)&adjT[((kgA >> 3) + c) * BM * 8 + mA * 8] = w8;
            }
        }
        // --- stage x rows k0..k0+31 (coalesced global, 3-way bf16 split) ---
        {
            float v[16];
            #pragma unroll
            for (int i = 0; i < 16; ++i)
                v[i] = xsrc[(size_t)(k0 + kgX + i) * F + nX];
            #pragma unroll
            for (int c = 0; c < 2; ++c) {
                short8 h1, h2, h3;
                #pragma unroll
                for (int j = 0; j < 8; ++j) {
                    float f = v[c * 8 + j];
                    unsigned short a1 = f2bf(f);
                    float r = f - bf2f(a1);
                    unsigned short a2 = f2bf(r);
                    float r2 = r - bf2f(a2);
                    h1[j] = (short)a1; h2[j] = (short)a2; h3[j] = (short)f2bf(r2);
                }
                int ko = (kgX >> 3) + c;
                *(short8*)&xs[0][ko * 1024 + nX * 8] = h1;
                *(short8*)&xs[1][ko * 1024 + nX * 8] = h2;
                *(short8*)&xs[2][ko * 1024 + nX * 8] = h3;
            }
        }
        __syncthreads();
        // --- MFMA: acc += AdjTile @ xsplit ---
        short8 afr[MT];
        #pragma unroll
        for (int mt = 0; mt < MT; ++mt)
            afr[mt] = *(const short8*)&adjT[(lane >> 4) * BM * 8 + (wv * RW + mt * 16 + (lane & 15)) * 8];
        #pragma unroll
        for (int s = 0; s < 3; ++s) {
            #pragma unroll
            for (int ct = 0; ct < 8; ++ct) {
                short8 bfr = *(const short8*)&xs[s][(lane >> 4) * 1024 + (ct * 16 + (lane & 15)) * 8];
                #pragma unroll
                for (int mt = 0; mt < MT; ++mt)
                    acc[mt][ct] = __builtin_amdgcn_mfma_f32_16x16x32_bf16(afr[mt], bfr, acc[mt][ct], 0, 0, 0);
            }
        }
    }

    // write agg rows (D: col=lane&15, row=(lane>>4)*4+reg)
    float* Ag = A + (size_t)g * 32768;
    #pragma unroll
    for (int mt = 0; mt < MT; ++mt) {
        int r0 = mbase + wv * RW + mt * 16 + (lane >> 4) * 4;
        #pragma unroll
        for (int ct = 0; ct < 8; ++ct) {
            int col = ct * 16 + (lane & 15);
            #pragma unroll
            for (int r = 0; r < 4; ++r)
                Ag[(size_t)(r0 + r) * F + col] = acc[mt][ct][r];
        }
    }
}

// -------------------- conv GEMM on MFMA: h = relu([X | AGG] @ [Wr;Wl] + b) -----------
// 2-way bf16 split of both operands, 3 MFMA passes (a1w1 + a2w1 + a1w2):
// rel err ~2^-17 -- far below top-k score gaps. W packed once per block into
// LDS as (hi|lo<<16) u32 in fragment-major [ko][jh][col][4] so B-frag reads
// are ds_read_b128 at the bank floor. A-tile staged per K-step as 2-split
// bf16 fragments. LDS 80 KB -> 2 blocks/CU.
template<int NS, bool FIRST>
__global__ __launch_bounds__(256) void k_gemm(const float* __restrict__ X,
                                              float* A,
                                              const float* __restrict__ Wr,
                                              const float* __restrict__ Wl,
                                              const float* __restrict__ bias) {
    constexpr int L2NS = (NS == 256) ? 8 : (NS == 128) ? 7 : 6;
    __shared__ unsigned Wp[32 * 2 * 128 * 4];  // [ko][jh][col][4j] (hi|lo<<16), 64 KB
    __shared__ short Af[2][4][128][8];         // [split][ko][row][8k], 16 KB
    const int t = threadIdx.x;
    const int m0 = blockIdx.x * 128;
    const int lane = t & 63, wv = t >> 6;

    // ---- prologue: pack W (both mats) 2-split into fragment-ready LDS ----
    {
        const int col = t & 127, half = t >> 7;  // half 0 -> Wr (k<128), 1 -> Wl
        const float* wsrc = half ? Wl : Wr;
        #pragma unroll 2
        for (int i = 0; i < 16; ++i) {
            int ko = half * 16 + i;
            unsigned q[8];
            #pragma unroll
            for (int j = 0; j < 8; ++j) {
                float f = wsrc[(size_t)(i * 8 + j) * 128 + col];
                unsigned short h1 = f2bf(f);
                unsigned short h2 = f2bf(f - bf2f(h1));
                q[j] = (unsigned)h1 | ((unsigned)h2 << 16);
            }
            *(uint4*)&Wp[((ko * 2 + 0) * 128 + col) * 4] = uint4{q[0], q[1], q[2], q[3]};
            *(uint4*)&Wp[((ko * 2 + 1) * 128 + col) * 4] = uint4{q[4], q[5], q[6], q[7]};
        }
    }

    f32x4 acc[2][8];
    #pragma unroll
    for (int i = 0; i < 2; ++i)
        #pragma unroll
        for (int c = 0; c < 8; ++c) acc[i][c] = f32x4{0.f, 0.f, 0.f, 0.f};

    // A staging: thread t loads row r_st = t>>1, 16 k's at (t&1)*16
    const int r_st = t >> 1;
    const int m_st = m0 + r_st;
    const int g_st = m_st >> L2NS, n_st = m_st & (NS - 1);
    const float* xrow = FIRST ? (X + (size_t)m_st * F)
                              : (A + (size_t)g_st * 32768 + (size_t)(128 + n_st) * F);
    const float* arow = A + (size_t)g_st * 32768 + (size_t)n_st * F;
    const int k16 = (t & 1) * 16;

    for (int kt = 0; kt < 8; ++kt) {
        __syncthreads();  // Af readers of prev iter done (and kt=0: Wp writes done)
        {
            const float* srow = ((kt < 4) ? (xrow + kt * 32) : (arow + (kt - 4) * 32)) + k16;
            float v[16];
            #pragma unroll
            for (int q = 0; q < 4; ++q) {
                float4 f4 = *(const float4*)(srow + q * 4);
                v[q * 4 + 0] = f4.x; v[q * 4 + 1] = f4.y; v[q * 4 + 2] = f4.z; v[q * 4 + 3] = f4.w;
            }
            #pragma unroll
            for (int c = 0; c < 2; ++c) {
                short8 h1, h2;
                #pragma unroll
                for (int j = 0; j < 8; ++j) {
                    float f = v[c * 8 + j];
                    unsigned short a1 = f2bf(f);
                    unsigned short a2 = f2bf(f - bf2f(a1));
                    h1[j] = (short)a1; h2[j] = (short)a2;
                }
                int ko = (t & 1) * 2 + c;
                *(short8*)&Af[0][ko][r_st][0] = h1;
                *(short8*)&Af[1][ko][r_st][0] = h2;
            }
        }
        __syncthreads();

        // A-frags for this wave
        short8 a1f[2], a2f[2];
        #pragma unroll
        for (int mt = 0; mt < 2; ++mt) {
            int row = wv * 32 + mt * 16 + (lane & 15);
            a1f[mt] = *(const short8*)&Af[0][lane >> 4][row][0];
            a2f[mt] = *(const short8*)&Af[1][lane >> 4][row][0];
        }
        const int kob = (kt * 4 + (lane >> 4)) * 2;
        #pragma unroll
        for (int ct = 0; ct < 8; ++ct) {
            int col = ct * 16 + (lane & 15);
            uint4 q0 = *(const uint4*)&Wp[((kob + 0) * 128 + col) * 4];
            uint4 q1 = *(const uint4*)&Wp[((kob + 1) * 128 + col) * 4];
            short8 w1, w2;
            w1[0] = (short)q0.x; w2[0] = (short)(q0.x >> 16);
            w1[1] = (short)q0.y; w2[1] = (short)(q0.y >> 16);
            w1[2] = (short)q0.z; w2[2] = (short)(q0.z >> 16);
            w1[3] = (short)q0.w; w2[3] = (short)(q0.w >> 16);
            w1[4] = (short)q1.x; w2[4] = (short)(q1.x >> 16);
            w1[5] = (short)q1.y; w2[5] = (short)(q1.y >> 16);
            w1[6] = (short)q1.z; w2[6] = (short)(q1.z >> 16);
            w1[7] = (short)q1.w; w2[7] = (short)(q1.w >> 16);
            #pragma unroll
            for (int mt = 0; mt < 2; ++mt) {
                acc[mt][ct] = __builtin_amdgcn_mfma_f32_16x16x32_bf16(a1f[mt], w1, acc[mt][ct], 0, 0, 0);
                acc[mt][ct] = __builtin_amdgcn_mfma_f32_16x16x32_bf16(a2f[mt], w1, acc[mt][ct], 0, 0, 0);
                acc[mt][ct] = __builtin_amdgcn_mfma_f32_16x16x32_bf16(a1f[mt], w2, acc[mt][ct], 0, 0, 0);
            }
        }
    }

    // epilogue: bias + relu, D: col=lane&15 (per ct), row=(lane>>4)*4+reg
    #pragma unroll
    for (int ct = 0; ct < 8; ++ct) {
        int col = ct * 16 + (lane & 15);
        float bv = bias[col];
        #pragma unroll
        for (int mt = 0; mt < 2; ++mt) {
            int r0 = m0 + wv * 32 + mt * 16 + (lane >> 4) * 4;
            #pragma unroll
            for (int r = 0; r < 4; ++r) {
                int m = r0 + r;
                int gg = m >> L2NS, nn = m & (NS - 1);
                A[(size_t)gg * 32768 + (size_t)nn * F + col] = fmaxf(acc[mt][ct][r] + bv, 0.f);
            }
        }
    }
}

// -------------------- top-k pool + readout + cmap update --------------------
template<int N, int K, int STAGE>
__global__ __launch_bounds__(256) void k_pool(float* __restrict__ A,
                                              float* __restrict__ R,
                                              int* __restrict__ cmap,
                                              const float* __restrict__ wp) {
    __shared__ float sc[256];
    __shared__ unsigned long long keys[256];
    __shared__ float hp[K * F];
    __shared__ int sel[K];
    __shared__ int inv[N];
    __shared__ float wn[F];
    __shared__ float snorm_s;
    const int g = blockIdx.x, t = threadIdx.x;
    const float* h = A + (size_t)g * 32768;

    if (t < 64) {
        float v = wp[t] * wp[t] + wp[t + 64] * wp[t + 64];
        #pragma unroll
        for (int o = 32; o; o >>= 1) v += __shfl_xor(v, o);
        if (t == 0) snorm_s = sqrtf(v);
    }
    __syncthreads();
    if (t < 128) wn[t] = wp[t] / snorm_s;
    __syncthreads();

    const int wid = t >> 6, lane = t & 63;
    for (int n = wid; n < N; n += 4) {
        float p = h[n * F + lane] * wn[lane] + h[n * F + 64 + lane] * wn[64 + lane];
        #pragma unroll
        for (int o = 32; o; o >>= 1) p += __shfl_xor(p, o);
        if (lane == 0) sc[n] = p;
    }
    __syncthreads();

    if (t < N) {
        unsigned u = __float_as_uint(sc[t]);
        u = (u & 0x80000000u) ? ~u : (u | 0x80000000u);
        keys[t] = ((unsigned long long)u << 32) | (unsigned)(~t);
    } else {
        keys[t] = 0ull;
    }
    __syncthreads();
    for (int kk = 2; kk <= 256; kk <<= 1) {
        for (int j = kk >> 1; j > 0; j >>= 1) {
            int ixj = t ^ j;
            if (ixj > t) {
                unsigned long long a = keys[t], b = keys[ixj];
                bool up = (t & kk) == 0;
                if (up ? (a < b) : (a > b)) { keys[t] = b; keys[ixj] = a; }
            }
            __syncthreads();
        }
    }

    if (t < K) sel[t] = (int)(~(unsigned)keys[t]);
    if (t < N) inv[t] = -1;
    __syncthreads();
    if (t < K) inv[sel[t]] = t;
    __syncthreads();

    {
        int c = (STAGE == 1) ? t : cmap[g * 256 + t];
        cmap[g * 256 + t] = (c >= 0) ? inv[c] : -1;
    }

    const int f = t & 127;
    for (int j = t >> 7; j < K; j += 2) {
        int n = sel[j];
        float gate = tanhf(sc[n]);
        hp[j * F + f] = h[n * F + f] * gate;
    }
    __syncthreads();

    if (STAGE < 3) {
        for (int j = t >> 7; j < K; j += 2)
            A[(size_t)g * 32768 + (size_t)(128 + j) * F + f] = hp[j * F + f];
    }

    if (t < 128) {
        float mx = -INFINITY, sm = 0.f;
        for (int j = 0; j < K; ++j) {
            float v = hp[j * F + t];
            mx = fmaxf(mx, v);
            sm += v;
        }
        R[(size_t)g * 768 + (STAGE - 1) * 256 + t] = mx;
        R[(size_t)g * 768 + (STAGE - 1) * 256 + 128 + t] = sm * (1.0f / K);
    }
}

// -------------------- final MLP + log_softmax --------------------
__global__ __launch_bounds__(128) void k_mlp(const float* __restrict__ R,
                                             const float* __restrict__ W1, const float* __restrict__ b1,
                                             const float* __restrict__ W2, const float* __restrict__ b2,
                                             const float* __restrict__ W3, const float* __restrict__ b3,
                                             float* __restrict__ out) {
    __shared__ float z[768];
    __shared__ float z2[128];
    __shared__ float z3[64];
    __shared__ float lg[10];
    __shared__ float lse;
    const int g = blockIdx.x, t = threadIdx.x;

    #pragma unroll
    for (int i = 0; i < 6; ++i) z[t + i * 128] = R[(size_t)g * 768 + t + i * 128];
    __syncthreads();

    float acc = b1[t];
    #pragma unroll 8
    for (int k = 0; k < 768; ++k) acc = fmaf(z[k], W1[k * 128 + t], acc);
    z2[t] = fmaxf(acc, 0.f);
    __syncthreads();

    if (t < 64) {
        float a2 = b2[t];
        #pragma unroll 8
        for (int k = 0; k < 128; ++k) a2 = fmaf(z2[k], W2[k * 64 + t], a2);
        z3[t] = fmaxf(a2, 0.f);
    }
    __syncthreads();

    if (t < 10) {
        float a3 = b3[t];
        #pragma unroll 8
        for (int k = 0; k < 64; ++k) a3 = fmaf(z3[k], W3[k * 10 + t], a3);
        lg[t] = a3;
    }
    __syncthreads();

    if (t == 0) {
        float m = lg[0];
        for (int c = 1; c < 10; ++c) m = fmaxf(m, lg[c]);
        float s = 0.f;
        for (int c = 0; c < 10; ++c) s += expf(lg[c] - m);
        lse = m + logf(s);
    }
    __syncthreads();
    if (t < 10) out[(size_t)g * 10 + t] = lg[t] - lse;
}

extern "C" void kernel_launch(void* const* d_in, const int* in_sizes, int n_in,
                              void* d_out, int out_size, void* d_ws, size_t ws_size,
                              hipStream_t stream) {
    (void)in_sizes; (void)n_in; (void)out_size; (void)ws_size;
    const float* x    = (const float*)d_in[0];
    const int*   src  = (const int*)d_in[1];
    const int*   dst  = (const int*)d_in[2];
    const float* Wr1  = (const float*)d_in[3];
    const float* Wrel1= (const float*)d_in[4];
    const float* b1   = (const float*)d_in[5];
    const float* wp1  = (const float*)d_in[6];
    const float* Wr2  = (const float*)d_in[7];
    const float* Wrel2= (const float*)d_in[8];
    const float* b2   = (const float*)d_in[9];
    const float* wp2  = (const float*)d_in[10];
    const float* Wr3  = (const float*)d_in[11];
    const float* Wrel3= (const float*)d_in[12];
    const float* b3   = (const float*)d_in[13];
    const float* wp3  = (const float*)d_in[14];
    const float* L1w  = (const float*)d_in[15];
    const float* L1b  = (const float*)d_in[16];
    const float* L2w  = (const float*)d_in[17];
    const float* L2b  = (const float*)d_in[18];
    const float* L3w  = (const float*)d_in[19];
    const float* L3b  = (const float*)d_in[20];

    float* A    = (float*)d_ws;                                       // G x 256 x 128 f32
    int*   cmap = (int*)((char*)d_ws + (size_t)G * 32768 * 4);        // G x 256 i32
    float* R    = (float*)((char*)d_ws + (size_t)G * 32768 * 4 + (size_t)G * 256 * 4);  // G x 768 f32
    float* out  = (float*)d_out;

    // stage 1
    k_agg<256, 128, false><<<G * 2, 256, 0, stream>>>(x, src, dst, nullptr, A);
    k_gemm<256, true><<<512, 256, 0, stream>>>(x, A, Wr1, Wrel1, b1);
    k_pool<256, 128, 1><<<G, 256, 0, stream>>>(A, R, cmap, wp1);
    // stage 2
    k_agg<128, 128, true><<<G, 256, 0, stream>>>(x, src, dst, cmap, A);
    k_gemm<128, false><<<256, 256, 0, stream>>>(nullptr, A, Wr2, Wrel2, b2);
    k_pool<128, 64, 2><<<G, 256, 0, stream>>>(A, R, cmap, wp2);
    // stage 3
    k_agg<64, 64, true><<<G, 256, 0, stream>>>(x, src, dst, cmap, A);
    k_gemm<64, false><<<128, 256, 0, stream>>>(nullptr, A, Wr3, Wrel3, b3);
    k_pool<64, 32, 3><<<G, 256, 0, stream>>>(A, R, cmap, wp3);
    // head
    k_mlp<<<G, 128, 0, stream>>>(R, L1w, L1b, L2w, L2b, L3w, L3b, out);
}

// Round 6
// 217.174 us; speedup vs baseline: 7.5191x; 1.2689x over previous
//
#include <hip/hip_runtime.h>
#include <cstdint>
#include <cstddef>

#define G 256
#define EPER 4096
#define F 128

typedef __attribute__((ext_vector_type(8))) short short8;
typedef __attribute__((ext_vector_type(4))) float f32x4;

__device__ inline unsigned short f2bf(float f) {
    unsigned u = __float_as_uint(f);
    u += 0x7FFFu + ((u >> 16) & 1u);
    return (unsigned short)(u >> 16);
}
__device__ inline float bf2f(unsigned short b) { return __uint_as_float(((unsigned)b) << 16); }

// -------------------- aggregation: agg = Adj @ x on MFMA --------------------
template<int NS, int BM, bool USE_MAP>
__global__ __launch_bounds__(256) void k_agg(const float* __restrict__ X,
                                             const int* __restrict__ src,
                                             const int* __restrict__ dst,
                                             const int* __restrict__ cmap,
                                             float* __restrict__ A) {
    constexpr bool SPLIT = (NS > BM);
    constexpr int RW = BM / 4;
    constexpr int MT = RW / 16;
    constexpr int NS4 = NS / 4;
    __shared__ unsigned adjc[BM * NS4];
    __shared__ short adjT[4 * BM * 8];
    __shared__ short xs[3][4 * 128 * 8];
    __shared__ int smap[256];

    const int b = blockIdx.x, t = threadIdx.x;
    const int g = SPLIT ? (b >> 1) : b;
    const int mbase = SPLIT ? (b & 1) * BM : 0;

    {
        uint4* z = (uint4*)adjc;
        #pragma unroll
        for (int i = t; i < BM * NS4 / 4; i += 256) z[i] = uint4{0, 0, 0, 0};
    }
    if (USE_MAP) smap[t] = cmap[g * 256 + t];
    __syncthreads();

    const int* sg = src + (size_t)g * EPER;
    const int* dg = dst + (size_t)g * EPER;
    #pragma unroll 4
    for (int j = 0; j < 16; ++j) {
        int e = j * 256 + t;
        int s = sg[e], d = dg[e];
        if (USE_MAP) { s = smap[s]; d = smap[d]; }
        int m = d - mbase;
        if (s >= 0 && (unsigned)m < (unsigned)BM) {
            int pos = (s + 4 * m) & (NS - 1);
            __hip_atomic_fetch_add(&adjc[m * NS4 + (pos >> 2)], 1u << ((pos & 3) * 8),
                                   __ATOMIC_RELAXED, __HIP_MEMORY_SCOPE_WORKGROUP);
        }
    }

    const float* xsrc = USE_MAP ? (A + (size_t)g * 32768 + 16384) : (X + (size_t)g * 32768);

    f32x4 acc[MT][8];
    #pragma unroll
    for (int i = 0; i < MT; ++i)
        #pragma unroll
        for (int c = 0; c < 8; ++c) acc[i][c] = f32x4{0.f, 0.f, 0.f, 0.f};

    const int lane = t & 63, wv = t >> 6;
    constexpr int TPR = 256 / BM;
    constexpr int CPT = 32 / TPR;
    const int mA = t / TPR, kgA = (t % TPR) * CPT;
    const int nX = t & 127, kgX = (t >> 7) * 16;

    for (int k0 = 0; k0 < NS; k0 += 32) {
        __syncthreads();
        {
            unsigned short cs[CPT];
            #pragma unroll
            for (int q = 0; q < CPT / 4; ++q) {
                unsigned w = adjc[mA * NS4 + ((((k0 + kgA) >> 2) + mA + q) & (NS4 - 1))];
                cs[q * 4 + 0] = f2bf((float)(w & 255u));
                cs[q * 4 + 1] = f2bf((float)((w >> 8) & 255u));
                cs[q * 4 + 2] = f2bf((float)((w >> 16) & 255u));
                cs[q * 4 + 3] = f2bf((float)(w >> 24));
            }
            #pragma unroll
            for (int c = 0; c < CPT / 8; ++c) {
                short8 w8;
                #pragma unroll
                for (int j = 0; j < 8; ++j) w8[j] = (short)cs[c * 8 + j];
                *(short8*)&adjT[((kgA >> 3) + c) * BM * 8 + mA * 8] = w8;
            }
        }
        {
            float v[16];
            #pragma unroll
            for (int i = 0; i < 16; ++i)
                v[i] = xsrc[(size_t)(k0 + kgX + i) * F + nX];
            #pragma unroll
            for (int c = 0; c < 2; ++c) {
                short8 h1, h2, h3;
                #pragma unroll
                for (int j = 0; j < 8; ++j) {
                    float f = v[c * 8 + j];
                    unsigned short a1 = f2bf(f);
                    float r = f - bf2f(a1);
                    unsigned short a2 = f2bf(r);
                    float r2 = r - bf2f(a2);
                    h1[j] = (short)a1; h2[j] = (short)a2; h3[j] = (short)f2bf(r2);
                }
                int ko = (kgX >> 3) + c;
                *(short8*)&xs[0][ko * 1024 + nX * 8] = h1;
                *(short8*)&xs[1][ko * 1024 + nX * 8] = h2;
                *(short8*)&xs[2][ko * 1024 + nX * 8] = h3;
            }
        }
        __syncthreads();
        short8 afr[MT];
        #pragma unroll
        for (int mt = 0; mt < MT; ++mt)
            afr[mt] = *(const short8*)&adjT[(lane >> 4) * BM * 8 + (wv * RW + mt * 16 + (lane & 15)) * 8];
        #pragma unroll
        for (int s = 0; s < 3; ++s) {
            #pragma unroll
            for (int ct = 0; ct < 8; ++ct) {
                short8 bfr = *(const short8*)&xs[s][(lane >> 4) * 1024 + (ct * 16 + (lane & 15)) * 8];
                #pragma unroll
                for (int mt = 0; mt < MT; ++mt)
                    acc[mt][ct] = __builtin_amdgcn_mfma_f32_16x16x32_bf16(afr[mt], bfr, acc[mt][ct], 0, 0, 0);
            }
        }
    }

    float* Ag = A + (size_t)g * 32768;
    #pragma unroll
    for (int mt = 0; mt < MT; ++mt) {
        int r0 = mbase + wv * RW + mt * 16 + (lane >> 4) * 4;
        #pragma unroll
        for (int ct = 0; ct < 8; ++ct) {
            int col = ct * 16 + (lane & 15);
            #pragma unroll
            for (int r = 0; r < 4; ++r)
                Ag[(size_t)(r0 + r) * F + col] = acc[mt][ct][r];
        }
    }
}

// -------------------- conv GEMM on MFMA: h = relu([X | AGG] @ [Wr;Wl] + b) -----------
// A 3-split (in-register, from fp32 LDS tile), W 2-split, 5 MFMA passes:
// a1w1+a2w1+a1w2+a2w2+a3w1 -> residual ~2^-26 (fp32-grade), keeps top-k stable.
template<int NS, bool FIRST>
__global__ __launch_bounds__(256) void k_gemm(const float* __restrict__ X,
                                              float* A,
                                              const float* __restrict__ Wr,
                                              const float* __restrict__ Wl,
                                              const float* __restrict__ bias) {
    constexpr int L2NS = (NS == 256) ? 8 : (NS == 128) ? 7 : 6;
    __shared__ unsigned Wp[32 * 2 * 128 * 4];  // [ko][jh][col][4j] (hi|lo<<16), 64 KB
    __shared__ float4 Af0[4][128];             // [ko][row] k 0..3, fp32
    __shared__ float4 Af1[4][128];             // [ko][row] k 4..7, fp32
    const int t = threadIdx.x;
    const int m0 = blockIdx.x * 128;
    const int lane = t & 63, wv = t >> 6;

    // ---- prologue: pack W (both mats) 2-split into fragment-ready LDS ----
    {
        const int col = t & 127, half = t >> 7;
        const float* wsrc = half ? Wl : Wr;
        #pragma unroll 2
        for (int i = 0; i < 16; ++i) {
            int ko = half * 16 + i;
            unsigned q[8];
            #pragma unroll
            for (int j = 0; j < 8; ++j) {
                float f = wsrc[(size_t)(i * 8 + j) * 128 + col];
                unsigned short h1 = f2bf(f);
                unsigned short h2 = f2bf(f - bf2f(h1));
                q[j] = (unsigned)h1 | ((unsigned)h2 << 16);
            }
            *(uint4*)&Wp[((ko * 2 + 0) * 128 + col) * 4] = uint4{q[0], q[1], q[2], q[3]};
            *(uint4*)&Wp[((ko * 2 + 1) * 128 + col) * 4] = uint4{q[4], q[5], q[6], q[7]};
        }
    }

    f32x4 acc[2][8];
    #pragma unroll
    for (int i = 0; i < 2; ++i)
        #pragma unroll
        for (int c = 0; c < 8; ++c) acc[i][c] = f32x4{0.f, 0.f, 0.f, 0.f};

    const int r_st = t >> 1;
    const int m_st = m0 + r_st;
    const int g_st = m_st >> L2NS, n_st = m_st & (NS - 1);
    const float* xrow = FIRST ? (X + (size_t)m_st * F)
                              : (A + (size_t)g_st * 32768 + (size_t)(128 + n_st) * F);
    const float* arow = A + (size_t)g_st * 32768 + (size_t)n_st * F;
    const int k16 = (t & 1) * 16;

    for (int kt = 0; kt < 8; ++kt) {
        __syncthreads();
        {
            const float* srow = ((kt < 4) ? (xrow + kt * 32) : (arow + (kt - 4) * 32)) + k16;
            #pragma unroll
            for (int c = 0; c < 2; ++c) {
                int ko = (t & 1) * 2 + c;
                Af0[ko][r_st] = *(const float4*)(srow + c * 8);
                Af1[ko][r_st] = *(const float4*)(srow + c * 8 + 4);
            }
        }
        __syncthreads();

        // A-frags: fp32 -> 3-way bf16 split in registers
        short8 a1f[2], a2f[2], a3f[2];
        #pragma unroll
        for (int mt = 0; mt < 2; ++mt) {
            int row = wv * 32 + mt * 16 + (lane & 15);
            float4 v0 = Af0[lane >> 4][row];
            float4 v1 = Af1[lane >> 4][row];
            float vv[8] = {v0.x, v0.y, v0.z, v0.w, v1.x, v1.y, v1.z, v1.w};
            #pragma unroll
            for (int j = 0; j < 8; ++j) {
                float f = vv[j];
                unsigned short a1 = f2bf(f);
                float r = f - bf2f(a1);
                unsigned short a2 = f2bf(r);
                float r2 = r - bf2f(a2);
                a1f[mt][j] = (short)a1; a2f[mt][j] = (short)a2; a3f[mt][j] = (short)f2bf(r2);
            }
        }
        const int kob = (kt * 4 + (lane >> 4)) * 2;
        #pragma unroll
        for (int ct = 0; ct < 8; ++ct) {
            int col = ct * 16 + (lane & 15);
            uint4 q0 = *(const uint4*)&Wp[((kob + 0) * 128 + col) * 4];
            uint4 q1 = *(const uint4*)&Wp[((kob + 1) * 128 + col) * 4];
            short8 w1, w2;
            w1[0] = (short)q0.x; w2[0] = (short)(q0.x >> 16);
            w1[1] = (short)q0.y; w2[1] = (short)(q0.y >> 16);
            w1[2] = (short)q0.z; w2[2] = (short)(q0.z >> 16);
            w1[3] = (short)q0.w; w2[3] = (short)(q0.w >> 16);
            w1[4] = (short)q1.x; w2[4] = (short)(q1.x >> 16);
            w1[5] = (short)q1.y; w2[5] = (short)(q1.y >> 16);
            w1[6] = (short)q1.z; w2[6] = (short)(q1.z >> 16);
            w1[7] = (short)q1.w; w2[7] = (short)(q1.w >> 16);
            #pragma unroll
            for (int mt = 0; mt < 2; ++mt) {
                acc[mt][ct] = __builtin_amdgcn_mfma_f32_16x16x32_bf16(a1f[mt], w1, acc[mt][ct], 0, 0, 0);
                acc[mt][ct] = __builtin_amdgcn_mfma_f32_16x16x32_bf16(a2f[mt], w1, acc[mt][ct], 0, 0, 0);
                acc[mt][ct] = __builtin_amdgcn_mfma_f32_16x16x32_bf16(a1f[mt], w2, acc[mt][ct], 0, 0, 0);
                acc[mt][ct] = __builtin_amdgcn_mfma_f32_16x16x32_bf16(a2f[mt], w2, acc[mt][ct], 0, 0, 0);
                acc[mt][ct] = __builtin_amdgcn_mfma_f32_16x16x32_bf16(a3f[mt], w1, acc[mt][ct], 0, 0, 0);
            }
        }
    }

    #pragma unroll
    for (int ct = 0; ct < 8; ++ct) {
        int col = ct * 16 + (lane & 15);
        float bv = bias[col];
        #pragma unroll
        for (int mt = 0; mt < 2; ++mt) {
            int r0 = m0 + wv * 32 + mt * 16 + (lane >> 4) * 4;
            #pragma unroll
            for (int r = 0; r < 4; ++r) {
                int m = r0 + r;
                int gg = m >> L2NS, nn = m & (NS - 1);
                A[(size_t)gg * 32768 + (size_t)nn * F + col] = fmaxf(acc[mt][ct][r] + bv, 0.f);
            }
        }
    }
}

// -------------------- top-k pool + readout + cmap update (1024 threads) --------------------
template<int N, int K, int STAGE>
__global__ __launch_bounds__(1024) void k_pool(float* __restrict__ A,
                                               float* __restrict__ R,
                                               int* __restrict__ cmap,
                                               const float* __restrict__ wp) {
    __shared__ float sc[N];
    __shared__ unsigned long long keys[N];
    __shared__ float hp[K * F];
    __shared__ int sel[K];
    __shared__ int inv[N];
    __shared__ float wn[F];
    __shared__ float gates[K];
    __shared__ float pmx[8 * F];
    __shared__ float psm[8 * F];
    __shared__ float snorm_s;
    const int g = blockIdx.x, t = threadIdx.x;
    const float* h = A + (size_t)g * 32768;
    const int lane = t & 63, wv16 = t >> 6;

    if (t < 64) {
        float v = wp[t] * wp[t] + wp[t + 64] * wp[t + 64];
        #pragma unroll
        for (int o = 32; o; o >>= 1) v += __shfl_xor(v, o);
        if (t == 0) snorm_s = sqrtf(v);
    }
    __syncthreads();
    if (t < 128) wn[t] = wp[t] / snorm_s;
    __syncthreads();

    // scores: 16 waves x 4 rows/wave per iter, 16-lane-group dot products
    {
        const int r16 = lane >> 4, l16 = lane & 15;
        float4 w0 = *(const float4*)&wn[l16 * 8];
        float4 w1 = *(const float4*)&wn[l16 * 8 + 4];
        #pragma unroll
        for (int n0 = 0; n0 < N; n0 += 64) {
            int r = n0 + wv16 * 4 + r16;
            const float* hr = h + (size_t)r * F + l16 * 8;
            float4 v0 = *(const float4*)hr;
            float4 v1 = *(const float4*)(hr + 4);
            float p = v0.x * w0.x + v0.y * w0.y + v0.z * w0.z + v0.w * w0.w
                    + v1.x * w1.x + v1.y * w1.y + v1.z * w1.z + v1.w * w1.w;
            p += __shfl_xor(p, 1); p += __shfl_xor(p, 2);
            p += __shfl_xor(p, 4); p += __shfl_xor(p, 8);
            if (l16 == 0) sc[r] = p;
        }
    }
    __syncthreads();

    // sort N keys descending: (order-preserving score bits, ties -> smaller idx)
    if (t < N) {
        unsigned u = __float_as_uint(sc[t]);
        u = (u & 0x80000000u) ? ~u : (u | 0x80000000u);
        keys[t] = ((unsigned long long)u << 32) | (unsigned)(~t);
    }
    __syncthreads();
    for (int kk = 2; kk <= N; kk <<= 1) {
        for (int j = kk >> 1; j > 0; j >>= 1) {
            if (t < N) {
                int ixj = t ^ j;
                if (ixj > t) {
                    unsigned long long a = keys[t], b = keys[ixj];
                    bool up = (t & kk) == 0;
                    if (up ? (a < b) : (a > b)) { keys[t] = b; keys[ixj] = a; }
                }
            }
            __syncthreads();
        }
    }

    if (t < K) sel[t] = (int)(~(unsigned)keys[t]);
    if (t < N) inv[t] = -1;
    __syncthreads();
    if (t < K) {
        inv[sel[t]] = t;
        gates[t] = tanhf(sc[sel[t]]);
    }
    __syncthreads();
    if (t < 256) {
        int c = (STAGE == 1) ? t : cmap[g * 256 + t];
        cmap[g * 256 + t] = (c >= 0) ? inv[c] : -1;
    }

    // gather gated rows into LDS + partial readout (8 segs x 128 feats)
    {
        const int f = t & 127, seg = t >> 7;
        float mx = -INFINITY, sm = 0.f;
        for (int j = seg; j < K; j += 8) {
            float v = h[(size_t)sel[j] * F + f] * gates[j];
            hp[j * F + f] = v;
            mx = fmaxf(mx, v);
            sm += v;
        }
        pmx[seg * F + f] = mx;
        psm[seg * F + f] = sm;
    }
    __syncthreads();

    if (t < 128) {
        float m = -INFINITY, s = 0.f;
        #pragma unroll
        for (int q = 0; q < 8; ++q) {
            m = fmaxf(m, pmx[q * F + t]);
            s += psm[q * F + t];
        }
        R[(size_t)g * 768 + (STAGE - 1) * 256 + t] = m;
        R[(size_t)g * 768 + (STAGE - 1) * 256 + 128 + t] = s * (1.0f / K);
    }

    if (STAGE < 3) {
        float4* dst = (float4*)(A + (size_t)g * 32768 + 128 * F);
        const float4* srcp = (const float4*)hp;
        for (int i = t; i < K * F / 4; i += 1024) dst[i] = srcp[i];
    }
}

// -------------------- final MLP + log_softmax --------------------
__global__ __launch_bounds__(128) void k_mlp(const float* __restrict__ R,
                                             const float* __restrict__ W1, const float* __restrict__ b1,
                                             const float* __restrict__ W2, const float* __restrict__ b2,
                                             const float* __restrict__ W3, const float* __restrict__ b3,
                                             float* __restrict__ out) {
    __shared__ float z[768];
    __shared__ float z2[128];
    __shared__ float z3[64];
    __shared__ float lg[10];
    __shared__ float lse;
    const int g = blockIdx.x, t = threadIdx.x;

    #pragma unroll
    for (int i = 0; i < 6; ++i) z[t + i * 128] = R[(size_t)g * 768 + t + i * 128];
    __syncthreads();

    float acc = b1[t];
    #pragma unroll 8
    for (int k = 0; k < 768; ++k) acc = fmaf(z[k], W1[k * 128 + t], acc);
    z2[t] = fmaxf(acc, 0.f);
    __syncthreads();

    if (t < 64) {
        float a2 = b2[t];
        #pragma unroll 8
        for (int k = 0; k < 128; ++k) a2 = fmaf(z2[k], W2[k * 64 + t], a2);
        z3[t] = fmaxf(a2, 0.f);
    }
    __syncthreads();

    if (t < 10) {
        float a3 = b3[t];
        #pragma unroll 8
        for (int k = 0; k < 64; ++k) a3 = fmaf(z3[k], W3[k * 10 + t], a3);
        lg[t] = a3;
    }
    __syncthreads();

    if (t == 0) {
        float m = lg[0];
        for (int c = 1; c < 10; ++c) m = fmaxf(m, lg[c]);
        float s = 0.f;
        for (int c = 0; c < 10; ++c) s += expf(lg[c] - m);
        lse = m + logf(s);
    }
    __syncthreads();
    if (t < 10) out[(size_t)g * 10 + t] = lg[t] - lse;
}

extern "C" void kernel_launch(void* const* d_in, const int* in_sizes, int n_in,
                              void* d_out, int out_size, void* d_ws, size_t ws_size,
                              hipStream_t stream) {
    (void)in_sizes; (void)n_in; (void)out_size; (void)ws_size;
    const float* x    = (const float*)d_in[0];
    const int*   src  = (const int*)d_in[1];
    const int*   dst  = (const int*)d_in[2];
    const float* Wr1  = (const float*)d_in[3];
    const float* Wrel1= (const float*)d_in[4];
    const float* b1   = (const float*)d_in[5];
    const float* wp1  = (const float*)d_in[6];
    const float* Wr2  = (const float*)d_in[7];
    const float* Wrel2= (const float*)d_in[8];
    const float* b2   = (const float*)d_in[9];
    const float* wp2  = (const float*)d_in[10];
    const float* Wr3  = (const float*)d_in[11];
    const float* Wrel3= (const float*)d_in[12];
    const float* b3   = (const float*)d_in[13];
    const float* wp3  = (const float*)d_in[14];
    const float* L1w  = (const float*)d_in[15];
    const float* L1b  = (const float*)d_in[16];
    const float* L2w  = (const float*)d_in[17];
    const float* L2b  = (const float*)d_in[18];
    const float* L3w  = (const float*)d_in[19];
    const float* L3b  = (const float*)d_in[20];

    float* A    = (float*)d_ws;                                       // G x 256 x 128 f32
    int*   cmap = (int*)((char*)d_ws + (size_t)G * 32768 * 4);        // G x 256 i32
    float* R    = (float*)((char*)d_ws + (size_t)G * 32768 * 4 + (size_t)G * 256 * 4);  // G x 768 f32
    float* out  = (float*)d_out;

    // stage 1
    k_agg<256, 128, false><<<G * 2, 256, 0, stream>>>(x, src, dst, nullptr, A);
    k_gemm<256, true><<<512, 256, 0, stream>>>(x, A, Wr1, Wrel1, b1);
    k_pool<256, 128, 1><<<G, 1024, 0, stream>>>(A, R, cmap, wp1);
    // stage 2
    k_agg<128, 128, true><<<G, 256, 0, stream>>>(x, src, dst, cmap, A);
    k_gemm<128, false><<<256, 256, 0, stream>>>(nullptr, A, Wr2, Wrel2, b2);
    k_pool<128, 64, 2><<<G, 1024, 0, stream>>>(A, R, cmap, wp2);
    // stage 3
    k_agg<64, 64, true><<<G, 256, 0, stream>>>(x, src, dst, cmap, A);
    k_gemm<64, false><<<128, 256, 0, stream>>>(nullptr, A, Wr3, Wrel3, b3);
    k_pool<64, 32, 3><<<G, 1024, 0, stream>>>(A, R, cmap, wp3);
    // head
    k_mlp<<<G, 128, 0, stream>>>(R, L1w, L1b, L2w, L2b, L3w, L3b, out);
}

// Round 7
// 189.232 us; speedup vs baseline: 8.6293x; 1.1477x over previous
//
#include <hip/hip_runtime.h>
#include <cstdint>
#include <cstddef>

#define G 256
#define EPER 4096
#define F 128

typedef __attribute__((ext_vector_type(8))) short short8;
typedef __attribute__((ext_vector_type(4))) float f32x4;

__device__ inline unsigned short f2bf(float f) {
    unsigned u = __float_as_uint(f);
    u += 0x7FFFu + ((u >> 16) & 1u);
    return (unsigned short)(u >> 16);
}
__device__ inline float bf2f(unsigned short b) { return __uint_as_float(((unsigned)b) << 16); }

// -------------------- aggregation: agg = Adj @ x on MFMA --------------------
template<int NS, int BM, bool USE_MAP>
__global__ __launch_bounds__(256) void k_agg(const float* __restrict__ X,
                                             const int* __restrict__ src,
                                             const int* __restrict__ dst,
                                             const int* __restrict__ cmap,
                                             float* __restrict__ A) {
    constexpr bool SPLIT = (NS > BM);
    constexpr int RW = BM / 4;
    constexpr int MT = RW / 16;
    constexpr int NS4 = NS / 4;
    __shared__ unsigned adjc[BM * NS4];
    __shared__ short adjT[4 * BM * 8];
    __shared__ short xs[3][4 * 128 * 8];
    __shared__ int smap[256];

    const int b = blockIdx.x, t = threadIdx.x;
    const int g = SPLIT ? (b >> 1) : b;
    const int mbase = SPLIT ? (b & 1) * BM : 0;

    {
        uint4* z = (uint4*)adjc;
        #pragma unroll
        for (int i = t; i < BM * NS4 / 4; i += 256) z[i] = uint4{0, 0, 0, 0};
    }
    if (USE_MAP) smap[t] = cmap[g * 256 + t];
    __syncthreads();

    const int* sg = src + (size_t)g * EPER;
    const int* dg = dst + (size_t)g * EPER;
    #pragma unroll 4
    for (int j = 0; j < 16; ++j) {
        int e = j * 256 + t;
        int s = sg[e], d = dg[e];
        if (USE_MAP) { s = smap[s]; d = smap[d]; }
        int m = d - mbase;
        if (s >= 0 && (unsigned)m < (unsigned)BM) {
            int pos = (s + 4 * m) & (NS - 1);
            __hip_atomic_fetch_add(&adjc[m * NS4 + (pos >> 2)], 1u << ((pos & 3) * 8),
                                   __ATOMIC_RELAXED, __HIP_MEMORY_SCOPE_WORKGROUP);
        }
    }

    const float* xsrc = USE_MAP ? (A + (size_t)g * 32768 + 16384) : (X + (size_t)g * 32768);

    f32x4 acc[MT][8];
    #pragma unroll
    for (int i = 0; i < MT; ++i)
        #pragma unroll
        for (int c = 0; c < 8; ++c) acc[i][c] = f32x4{0.f, 0.f, 0.f, 0.f};

    const int lane = t & 63, wv = t >> 6;
    constexpr int TPR = 256 / BM;
    constexpr int CPT = 32 / TPR;
    const int mA = t / TPR, kgA = (t % TPR) * CPT;
    const int nX = t & 127, kgX = (t >> 7) * 16;

    for (int k0 = 0; k0 < NS; k0 += 32) {
        __syncthreads();
        {
            unsigned short cs[CPT];
            #pragma unroll
            for (int q = 0; q < CPT / 4; ++q) {
                unsigned w = adjc[mA * NS4 + ((((k0 + kgA) >> 2) + mA + q) & (NS4 - 1))];
                cs[q * 4 + 0] = f2bf((float)(w & 255u));
                cs[q * 4 + 1] = f2bf((float)((w >> 8) & 255u));
                cs[q * 4 + 2] = f2bf((float)((w >> 16) & 255u));
                cs[q * 4 + 3] = f2bf((float)(w >> 24));
            }
            #pragma unroll
            for (int c = 0; c < CPT / 8; ++c) {
                short8 w8;
                #pragma unroll
                for (int j = 0; j < 8; ++j) w8[j] = (short)cs[c * 8 + j];
                *(short8*)&adjT[((kgA >> 3) + c) * BM * 8 + mA * 8] = w8;
            }
        }
        {
            float v[16];
            #pragma unroll
            for (int i = 0; i < 16; ++i)
                v[i] = xsrc[(size_t)(k0 + kgX + i) * F + nX];
            #pragma unroll
            for (int c = 0; c < 2; ++c) {
                short8 h1, h2, h3;
                #pragma unroll
                for (int j = 0; j < 8; ++j) {
                    float f = v[c * 8 + j];
                    unsigned short a1 = f2bf(f);
                    float r = f - bf2f(a1);
                    unsigned short a2 = f2bf(r);
                    float r2 = r - bf2f(a2);
                    h1[j] = (short)a1; h2[j] = (short)a2; h3[j] = (short)f2bf(r2);
                }
                int ko = (kgX >> 3) + c;
                *(short8*)&xs[0][ko * 1024 + nX * 8] = h1;
                *(short8*)&xs[1][ko * 1024 + nX * 8] = h2;
                *(short8*)&xs[2][ko * 1024 + nX * 8] = h3;
            }
        }
        __syncthreads();
        short8 afr[MT];
        #pragma unroll
        for (int mt = 0; mt < MT; ++mt)
            afr[mt] = *(const short8*)&adjT[(lane >> 4) * BM * 8 + (wv * RW + mt * 16 + (lane & 15)) * 8];
        #pragma unroll
        for (int s = 0; s < 3; ++s) {
            #pragma unroll
            for (int ct = 0; ct < 8; ++ct) {
                short8 bfr = *(const short8*)&xs[s][(lane >> 4) * 1024 + (ct * 16 + (lane & 15)) * 8];
                #pragma unroll
                for (int mt = 0; mt < MT; ++mt)
                    acc[mt][ct] = __builtin_amdgcn_mfma_f32_16x16x32_bf16(afr[mt], bfr, acc[mt][ct], 0, 0, 0);
            }
        }
    }

    float* Ag = A + (size_t)g * 32768;
    #pragma unroll
    for (int mt = 0; mt < MT; ++mt) {
        int r0 = mbase + wv * RW + mt * 16 + (lane >> 4) * 4;
        #pragma unroll
        for (int ct = 0; ct < 8; ++ct) {
            int col = ct * 16 + (lane & 15);
            #pragma unroll
            for (int r = 0; r < 4; ++r)
                Ag[(size_t)(r0 + r) * F + col] = acc[mt][ct][r];
        }
    }
}

// -------------------- conv GEMM on MFMA: h = relu([X | AGG] @ [Wr;Wl] + b) -----------
// A 3-split (in-register, from fp32 LDS tile), W 2-split, 5 MFMA passes:
// a1w1+a2w1+a1w2+a2w2+a3w1 -> residual ~2^-26 (fp32-grade), keeps top-k stable.
template<int NS, bool FIRST>
__global__ __launch_bounds__(256) void k_gemm(const float* __restrict__ X,
                                              float* A,
                                              const float* __restrict__ Wr,
                                              const float* __restrict__ Wl,
                                              const float* __restrict__ bias) {
    constexpr int L2NS = (NS == 256) ? 8 : (NS == 128) ? 7 : 6;
    __shared__ unsigned Wp[32 * 2 * 128 * 4];  // [ko][jh][col][4j] (hi|lo<<16), 64 KB
    __shared__ float4 Af0[4][128];             // [ko][row] k 0..3, fp32
    __shared__ float4 Af1[4][128];             // [ko][row] k 4..7, fp32
    const int t = threadIdx.x;
    const int m0 = blockIdx.x * 128;
    const int lane = t & 63, wv = t >> 6;

    // ---- prologue: pack W (both mats) 2-split into fragment-ready LDS ----
    {
        const int col = t & 127, half = t >> 7;
        const float* wsrc = half ? Wl : Wr;
        #pragma unroll 2
        for (int i = 0; i < 16; ++i) {
            int ko = half * 16 + i;
            unsigned q[8];
            #pragma unroll
            for (int j = 0; j < 8; ++j) {
                float f = wsrc[(size_t)(i * 8 + j) * 128 + col];
                unsigned short h1 = f2bf(f);
                unsigned short h2 = f2bf(f - bf2f(h1));
                q[j] = (unsigned)h1 | ((unsigned)h2 << 16);
            }
            *(uint4*)&Wp[((ko * 2 + 0) * 128 + col) * 4] = uint4{q[0], q[1], q[2], q[3]};
            *(uint4*)&Wp[((ko * 2 + 1) * 128 + col) * 4] = uint4{q[4], q[5], q[6], q[7]};
        }
    }

    f32x4 acc[2][8];
    #pragma unroll
    for (int i = 0; i < 2; ++i)
        #pragma unroll
        for (int c = 0; c < 8; ++c) acc[i][c] = f32x4{0.f, 0.f, 0.f, 0.f};

    const int r_st = t >> 1;
    const int m_st = m0 + r_st;
    const int g_st = m_st >> L2NS, n_st = m_st & (NS - 1);
    const float* xrow = FIRST ? (X + (size_t)m_st * F)
                              : (A + (size_t)g_st * 32768 + (size_t)(128 + n_st) * F);
    const float* arow = A + (size_t)g_st * 32768 + (size_t)n_st * F;
    const int k16 = (t & 1) * 16;

    for (int kt = 0; kt < 8; ++kt) {
        __syncthreads();
        {
            const float* srow = ((kt < 4) ? (xrow + kt * 32) : (arow + (kt - 4) * 32)) + k16;
            #pragma unroll
            for (int c = 0; c < 2; ++c) {
                int ko = (t & 1) * 2 + c;
                Af0[ko][r_st] = *(const float4*)(srow + c * 8);
                Af1[ko][r_st] = *(const float4*)(srow + c * 8 + 4);
            }
        }
        __syncthreads();

        // A-frags: fp32 -> 3-way bf16 split in registers
        short8 a1f[2], a2f[2], a3f[2];
        #pragma unroll
        for (int mt = 0; mt < 2; ++mt) {
            int row = wv * 32 + mt * 16 + (lane & 15);
            float4 v0 = Af0[lane >> 4][row];
            float4 v1 = Af1[lane >> 4][row];
            float vv[8] = {v0.x, v0.y, v0.z, v0.w, v1.x, v1.y, v1.z, v1.w};
            #pragma unroll
            for (int j = 0; j < 8; ++j) {
                float f = vv[j];
                unsigned short a1 = f2bf(f);
                float r = f - bf2f(a1);
                unsigned short a2 = f2bf(r);
                float r2 = r - bf2f(a2);
                a1f[mt][j] = (short)a1; a2f[mt][j] = (short)a2; a3f[mt][j] = (short)f2bf(r2);
            }
        }
        const int kob = (kt * 4 + (lane >> 4)) * 2;
        #pragma unroll
        for (int ct = 0; ct < 8; ++ct) {
            int col = ct * 16 + (lane & 15);
            uint4 q0 = *(const uint4*)&Wp[((kob + 0) * 128 + col) * 4];
            uint4 q1 = *(const uint4*)&Wp[((kob + 1) * 128 + col) * 4];
            short8 w1, w2;
            w1[0] = (short)q0.x; w2[0] = (short)(q0.x >> 16);
            w1[1] = (short)q0.y; w2[1] = (short)(q0.y >> 16);
            w1[2] = (short)q0.z; w2[2] = (short)(q0.z >> 16);
            w1[3] = (short)q0.w; w2[3] = (short)(q0.w >> 16);
            w1[4] = (short)q1.x; w2[4] = (short)(q1.x >> 16);
            w1[5] = (short)q1.y; w2[5] = (short)(q1.y >> 16);
            w1[6] = (short)q1.z; w2[6] = (short)(q1.z >> 16);
            w1[7] = (short)q1.w; w2[7] = (short)(q1.w >> 16);
            #pragma unroll
            for (int mt = 0; mt < 2; ++mt) {
                acc[mt][ct] = __builtin_amdgcn_mfma_f32_16x16x32_bf16(a1f[mt], w1, acc[mt][ct], 0, 0, 0);
                acc[mt][ct] = __builtin_amdgcn_mfma_f32_16x16x32_bf16(a2f[mt], w1, acc[mt][ct], 0, 0, 0);
                acc[mt][ct] = __builtin_amdgcn_mfma_f32_16x16x32_bf16(a1f[mt], w2, acc[mt][ct], 0, 0, 0);
                acc[mt][ct] = __builtin_amdgcn_mfma_f32_16x16x32_bf16(a2f[mt], w2, acc[mt][ct], 0, 0, 0);
                acc[mt][ct] = __builtin_amdgcn_mfma_f32_16x16x32_bf16(a3f[mt], w1, acc[mt][ct], 0, 0, 0);
            }
        }
    }

    #pragma unroll
    for (int ct = 0; ct < 8; ++ct) {
        int col = ct * 16 + (lane & 15);
        float bv = bias[col];
        #pragma unroll
        for (int mt = 0; mt < 2; ++mt) {
            int r0 = m0 + wv * 32 + mt * 16 + (lane >> 4) * 4;
            #pragma unroll
            for (int r = 0; r < 4; ++r) {
                int m = r0 + r;
                int gg = m >> L2NS, nn = m & (NS - 1);
                A[(size_t)gg * 32768 + (size_t)nn * F + col] = fmaxf(acc[mt][ct][r] + bv, 0.f);
            }
        }
    }
}

// -------------------- top-k pool + readout + cmap update (1024 threads) --------------------
template<int N, int K, int STAGE>
__global__ __launch_bounds__(1024) void k_pool(float* __restrict__ A,
                                               float* __restrict__ R,
                                               int* __restrict__ cmap,
                                               const float* __restrict__ wp) {
    __shared__ float sc[N];
    __shared__ unsigned long long keys[N];
    __shared__ float hp[K * F];
    __shared__ int sel[K];
    __shared__ int inv[N];
    __shared__ float wn[F];
    __shared__ float gates[K];
    __shared__ float pmx[8 * F];
    __shared__ float psm[8 * F];
    __shared__ float snorm_s;
    const int g = blockIdx.x, t = threadIdx.x;
    const float* h = A + (size_t)g * 32768;
    const int lane = t & 63, wv16 = t >> 6;

    if (t < 64) {
        float v = wp[t] * wp[t] + wp[t + 64] * wp[t + 64];
        #pragma unroll
        for (int o = 32; o; o >>= 1) v += __shfl_xor(v, o);
        if (t == 0) snorm_s = sqrtf(v);
    }
    __syncthreads();
    if (t < 128) wn[t] = wp[t] / snorm_s;
    __syncthreads();

    // scores: 16 waves x 4 rows/wave per iter, 16-lane-group dot products
    {
        const int r16 = lane >> 4, l16 = lane & 15;
        float4 w0 = *(const float4*)&wn[l16 * 8];
        float4 w1 = *(const float4*)&wn[l16 * 8 + 4];
        #pragma unroll
        for (int n0 = 0; n0 < N; n0 += 64) {
            int r = n0 + wv16 * 4 + r16;
            const float* hr = h + (size_t)r * F + l16 * 8;
            float4 v0 = *(const float4*)hr;
            float4 v1 = *(const float4*)(hr + 4);
            float p = v0.x * w0.x + v0.y * w0.y + v0.z * w0.z + v0.w * w0.w
                    + v1.x * w1.x + v1.y * w1.y + v1.z * w1.z + v1.w * w1.w;
            p += __shfl_xor(p, 1); p += __shfl_xor(p, 2);
            p += __shfl_xor(p, 4); p += __shfl_xor(p, 8);
            if (l16 == 0) sc[r] = p;
        }
    }
    __syncthreads();

    // sort N keys descending: (order-preserving score bits, ties -> smaller idx)
    if (t < N) {
        unsigned u = __float_as_uint(sc[t]);
        u = (u & 0x80000000u) ? ~u : (u | 0x80000000u);
        keys[t] = ((unsigned long long)u << 32) | (unsigned)(~t);
    }
    __syncthreads();
    for (int kk = 2; kk <= N; kk <<= 1) {
        for (int j = kk >> 1; j > 0; j >>= 1) {
            if (t < N) {
                int ixj = t ^ j;
                if (ixj > t) {
                    unsigned long long a = keys[t], b = keys[ixj];
                    bool up = (t & kk) == 0;
                    if (up ? (a < b) : (a > b)) { keys[t] = b; keys[ixj] = a; }
                }
            }
            __syncthreads();
        }
    }

    if (t < K) sel[t] = (int)(~(unsigned)keys[t]);
    if (t < N) inv[t] = -1;
    __syncthreads();
    if (t < K) {
        inv[sel[t]] = t;
        gates[t] = tanhf(sc[sel[t]]);
    }
    __syncthreads();
    if (t < 256) {
        int c = (STAGE == 1) ? t : cmap[g * 256 + t];
        cmap[g * 256 + t] = (c >= 0) ? inv[c] : -1;
    }

    // gather gated rows into LDS + partial readout (8 segs x 128 feats)
    {
        const int f = t & 127, seg = t >> 7;
        float mx = -INFINITY, sm = 0.f;
        for (int j = seg; j < K; j += 8) {
            float v = h[(size_t)sel[j] * F + f] * gates[j];
            hp[j * F + f] = v;
            mx = fmaxf(mx, v);
            sm += v;
        }
        pmx[seg * F + f] = mx;
        psm[seg * F + f] = sm;
    }
    __syncthreads();

    if (t < 128) {
        float m = -INFINITY, s = 0.f;
        #pragma unroll
        for (int q = 0; q < 8; ++q) {
            m = fmaxf(m, pmx[q * F + t]);
            s += psm[q * F + t];
        }
        R[(size_t)g * 768 + (STAGE - 1) * 256 + t] = m;
        R[(size_t)g * 768 + (STAGE - 1) * 256 + 128 + t] = s * (1.0f / K);
    }

    if (STAGE < 3) {
        float4* dst = (float4*)(A + (size_t)g * 32768 + 128 * F);
        const float4* srcp = (const float4*)hp;
        for (int i = t; i < K * F / 4; i += 1024) dst[i] = srcp[i];
    }
}

// -------------------- final MLP + log_softmax (split-K, 1024 threads) --------------------
__global__ __launch_bounds__(1024) void k_mlp(const float* __restrict__ R,
                                              const float* __restrict__ W1, const float* __restrict__ b1,
                                              const float* __restrict__ W2, const float* __restrict__ b2,
                                              const float* __restrict__ W3, const float* __restrict__ b3,
                                              float* __restrict__ out) {
    __shared__ float z[768];
    __shared__ float part[8][128];
    __shared__ float z2[128];
    __shared__ float z3[64];
    __shared__ float lg[10];
    __shared__ float lse;
    const int g = blockIdx.x, t = threadIdx.x;

    if (t < 768) z[t] = R[(size_t)g * 768 + t];
    __syncthreads();

    // layer 1: 8 k-segments x 128 features (chain 96 instead of 768)
    {
        const int f = t & 127, seg = t >> 7;
        float acc = 0.f;
        const float* w = W1 + (size_t)(seg * 96) * 128 + f;
        const float* zz = z + seg * 96;
        #pragma unroll 8
        for (int k = 0; k < 96; ++k) acc = fmaf(zz[k], w[(size_t)k * 128], acc);
        part[seg][f] = acc;
    }
    __syncthreads();
    if (t < 128) {
        float a = b1[t];
        #pragma unroll
        for (int q = 0; q < 8; ++q) a += part[q][t];
        z2[t] = fmaxf(a, 0.f);
    }
    __syncthreads();

    // layer 2: 8 k-segments x 64 features (chain 16)
    if (t < 512) {
        const int f = t & 63, seg = t >> 6;
        float acc = 0.f;
        const float* w = W2 + (size_t)(seg * 16) * 64 + f;
        const float* zz = z2 + seg * 16;
        #pragma unroll
        for (int k = 0; k < 16; ++k) acc = fmaf(zz[k], w[(size_t)k * 64], acc);
        part[seg][f] = acc;
    }
    __syncthreads();
    if (t < 64) {
        float a = b2[t];
        #pragma unroll
        for (int q = 0; q < 8; ++q) a += part[q][t];
        z3[t] = fmaxf(a, 0.f);
    }
    __syncthreads();

    if (t < 10) {
        float a3 = b3[t];
        #pragma unroll 8
        for (int k = 0; k < 64; ++k) a3 = fmaf(z3[k], W3[(size_t)k * 10 + t], a3);
        lg[t] = a3;
    }
    __syncthreads();

    if (t == 0) {
        float m = lg[0];
        for (int c = 1; c < 10; ++c) m = fmaxf(m, lg[c]);
        float s = 0.f;
        for (int c = 0; c < 10; ++c) s += expf(lg[c] - m);
        lse = m + logf(s);
    }
    __syncthreads();
    if (t < 10) out[(size_t)g * 10 + t] = lg[t] - lse;
}

extern "C" void kernel_launch(void* const* d_in, const int* in_sizes, int n_in,
                              void* d_out, int out_size, void* d_ws, size_t ws_size,
                              hipStream_t stream) {
    (void)in_sizes; (void)n_in; (void)out_size; (void)ws_size;
    const float* x    = (const float*)d_in[0];
    const int*   src  = (const int*)d_in[1];
    const int*   dst  = (const int*)d_in[2];
    const float* Wr1  = (const float*)d_in[3];
    const float* Wrel1= (const float*)d_in[4];
    const float* b1   = (const float*)d_in[5];
    const float* wp1  = (const float*)d_in[6];
    const float* Wr2  = (const float*)d_in[7];
    const float* Wrel2= (const float*)d_in[8];
    const float* b2   = (const float*)d_in[9];
    const float* wp2  = (const float*)d_in[10];
    const float* Wr3  = (const float*)d_in[11];
    const float* Wrel3= (const float*)d_in[12];
    const float* b3   = (const float*)d_in[13];
    const float* wp3  = (const float*)d_in[14];
    const float* L1w  = (const float*)d_in[15];
    const float* L1b  = (const float*)d_in[16];
    const float* L2w  = (const float*)d_in[17];
    const float* L2b  = (const float*)d_in[18];
    const float* L3w  = (const float*)d_in[19];
    const float* L3b  = (const float*)d_in[20];

    float* A    = (float*)d_ws;                                       // G x 256 x 128 f32
    int*   cmap = (int*)((char*)d_ws + (size_t)G * 32768 * 4);        // G x 256 i32
    float* R    = (float*)((char*)d_ws + (size_t)G * 32768 * 4 + (size_t)G * 256 * 4);  // G x 768 f32
    float* out  = (float*)d_out;

    // stage 1
    k_agg<256, 128, false><<<G * 2, 256, 0, stream>>>(x, src, dst, nullptr, A);
    k_gemm<256, true><<<512, 256, 0, stream>>>(x, A, Wr1, Wrel1, b1);
    k_pool<256, 128, 1><<<G, 1024, 0, stream>>>(A, R, cmap, wp1);
    // stage 2
    k_agg<128, 128, true><<<G, 256, 0, stream>>>(x, src, dst, cmap, A);
    k_gemm<128, false><<<256, 256, 0, stream>>>(nullptr, A, Wr2, Wrel2, b2);
    k_pool<128, 64, 2><<<G, 1024, 0, stream>>>(A, R, cmap, wp2);
    // stage 3
    k_agg<64, 64, true><<<G, 256, 0, stream>>>(x, src, dst, cmap, A);
    k_gemm<64, false><<<128, 256, 0, stream>>>(nullptr, A, Wr3, Wrel3, b3);
    k_pool<64, 32, 3><<<G, 1024, 0, stream>>>(A, R, cmap, wp3);
    // head
    k_mlp<<<G, 1024, 0, stream>>>(R, L1w, L1b, L2w, L2b, L3w, L3b, out);
}

// Round 8
// 163.884 us; speedup vs baseline: 9.9640x; 1.1547x over previous
//
#include <hip/hip_runtime.h>
#include <cstdint>
#include <cstddef>

#define G 256
#define EPER 4096
#define F 128

typedef __attribute__((ext_vector_type(8))) short short8;
typedef __attribute__((ext_vector_type(4))) float f32x4;

__device__ inline unsigned short f2bf(float f) {
    unsigned u = __float_as_uint(f);
    u += 0x7FFFu + ((u >> 16) & 1u);
    return (unsigned short)(u >> 16);
}
__device__ inline float bf2f(unsigned short b) { return __uint_as_float(((unsigned)b) << 16); }

// -------------------- aggregation: agg = Adj @ x on MFMA --------------------
template<int NS, int BM, bool USE_MAP>
__global__ __launch_bounds__(256) void k_agg(const float* __restrict__ X,
                                             const int* __restrict__ src,
                                             const int* __restrict__ dst,
                                             const int* __restrict__ cmap,
                                             float* __restrict__ A) {
    constexpr bool SPLIT = (NS > BM);
    constexpr int RW = BM / 4;
    constexpr int MT = RW / 16;
    constexpr int NS4 = NS / 4;
    __shared__ unsigned adjc[BM * NS4];
    __shared__ short adjT[4 * BM * 8];
    __shared__ short xs[3][4 * 128 * 8];
    __shared__ int smap[256];

    const int b = blockIdx.x, t = threadIdx.x;
    const int g = SPLIT ? (b >> 1) : b;
    const int mbase = SPLIT ? (b & 1) * BM : 0;

    {
        uint4* z = (uint4*)adjc;
        #pragma unroll
        for (int i = t; i < BM * NS4 / 4; i += 256) z[i] = uint4{0, 0, 0, 0};
    }
    if (USE_MAP) smap[t] = cmap[g * 256 + t];
    __syncthreads();

    const int* sg = src + (size_t)g * EPER;
    const int* dg = dst + (size_t)g * EPER;
    #pragma unroll 4
    for (int j = 0; j < 16; ++j) {
        int e = j * 256 + t;
        int s = sg[e], d = dg[e];
        if (USE_MAP) { s = smap[s]; d = smap[d]; }
        int m = d - mbase;
        if (s >= 0 && (unsigned)m < (unsigned)BM) {
            int pos = (s + 4 * m) & (NS - 1);
            __hip_atomic_fetch_add(&adjc[m * NS4 + (pos >> 2)], 1u << ((pos & 3) * 8),
                                   __ATOMIC_RELAXED, __HIP_MEMORY_SCOPE_WORKGROUP);
        }
    }

    const float* xsrc = USE_MAP ? (A + (size_t)g * 32768 + 16384) : (X + (size_t)g * 32768);

    f32x4 acc[MT][8];
    #pragma unroll
    for (int i = 0; i < MT; ++i)
        #pragma unroll
        for (int c = 0; c < 8; ++c) acc[i][c] = f32x4{0.f, 0.f, 0.f, 0.f};

    const int lane = t & 63, wv = t >> 6;
    constexpr int TPR = 256 / BM;
    constexpr int CPT = 32 / TPR;
    const int mA = t / TPR, kgA = (t % TPR) * CPT;
    const int nX = t & 127, kgX = (t >> 7) * 16;

    for (int k0 = 0; k0 < NS; k0 += 32) {
        __syncthreads();
        {
            unsigned short cs[CPT];
            #pragma unroll
            for (int q = 0; q < CPT / 4; ++q) {
                unsigned w = adjc[mA * NS4 + ((((k0 + kgA) >> 2) + mA + q) & (NS4 - 1))];
                cs[q * 4 + 0] = f2bf((float)(w & 255u));
                cs[q * 4 + 1] = f2bf((float)((w >> 8) & 255u));
                cs[q * 4 + 2] = f2bf((float)((w >> 16) & 255u));
                cs[q * 4 + 3] = f2bf((float)(w >> 24));
            }
            #pragma unroll
            for (int c = 0; c < CPT / 8; ++c) {
                short8 w8;
                #pragma unroll
                for (int j = 0; j < 8; ++j) w8[j] = (short)cs[c * 8 + j];
                *(short8*)&adjT[((kgA >> 3) + c) * BM * 8 + mA * 8] = w8;
            }
        }
        {
            float v[16];
            #pragma unroll
            for (int i = 0; i < 16; ++i)
                v[i] = xsrc[(size_t)(k0 + kgX + i) * F + nX];
            #pragma unroll
            for (int c = 0; c < 2; ++c) {
                short8 h1, h2, h3;
                #pragma unroll
                for (int j = 0; j < 8; ++j) {
                    float f = v[c * 8 + j];
                    unsigned short a1 = f2bf(f);
                    float r = f - bf2f(a1);
                    unsigned short a2 = f2bf(r);
                    float r2 = r - bf2f(a2);
                    h1[j] = (short)a1; h2[j] = (short)a2; h3[j] = (short)f2bf(r2);
                }
                int ko = (kgX >> 3) + c;
                *(short8*)&xs[0][ko * 1024 + nX * 8] = h1;
                *(short8*)&xs[1][ko * 1024 + nX * 8] = h2;
                *(short8*)&xs[2][ko * 1024 + nX * 8] = h3;
            }
        }
        __syncthreads();
        short8 afr[MT];
        #pragma unroll
        for (int mt = 0; mt < MT; ++mt)
            afr[mt] = *(const short8*)&adjT[(lane >> 4) * BM * 8 + (wv * RW + mt * 16 + (lane & 15)) * 8];
        #pragma unroll
        for (int s = 0; s < 3; ++s) {
            #pragma unroll
            for (int ct = 0; ct < 8; ++ct) {
                short8 bfr = *(const short8*)&xs[s][(lane >> 4) * 1024 + (ct * 16 + (lane & 15)) * 8];
                #pragma unroll
                for (int mt = 0; mt < MT; ++mt)
                    acc[mt][ct] = __builtin_amdgcn_mfma_f32_16x16x32_bf16(afr[mt], bfr, acc[mt][ct], 0, 0, 0);
            }
        }
    }

    float* Ag = A + (size_t)g * 32768;
    #pragma unroll
    for (int mt = 0; mt < MT; ++mt) {
        int r0 = mbase + wv * RW + mt * 16 + (lane >> 4) * 4;
        #pragma unroll
        for (int ct = 0; ct < 8; ++ct) {
            int col = ct * 16 + (lane & 15);
            #pragma unroll
            for (int r = 0; r < 4; ++r)
                Ag[(size_t)(r0 + r) * F + col] = acc[mt][ct][r];
        }
    }
}

// -------------------- conv GEMM on MFMA: h = relu([X | AGG] @ [Wr;Wl] + b) -----------
// 512 threads / 8 waves (2 per SIMD); wave tile 32 rows x 64 cols (mt2 x ct4).
// W pre-split into bf16 fragment LDS (Whi/Wlo, +8-bank skew per ko row);
// A pre-split during staging. 3 MFMA passes (a1w1+a2w1+a1w2, ~2^-17 rel —
// same accuracy class as R5 which measured absmax 0.625).
template<int NS, bool FIRST>
__global__ __launch_bounds__(512) void k_gemm(const float* __restrict__ X,
                                              float* A,
                                              const float* __restrict__ Wr,
                                              const float* __restrict__ Wl,
                                              const float* __restrict__ bias) {
    constexpr int L2NS = (NS == 256) ? 8 : (NS == 128) ? 7 : 6;
    __shared__ uint4 Whi[32][130];    // [ko][col] short8 hi-frags, 65 KB
    __shared__ uint4 Wlo[32][130];    // lo-frags
    __shared__ uint4 Afs[2][4][130];  // [split][ko][row] A-frags for current 32-k step
    const int t = threadIdx.x;
    const int m0 = blockIdx.x * 128;
    const int lane = t & 63, wv = t >> 6;
    const int wr = wv >> 1, wc = wv & 1;
    const int l15 = lane & 15, lko = lane >> 4;

    // ---- prologue: pack W (Wr then Wl) 2-split into fragment LDS ----
    {
        const int col = t & 127, grp = t >> 7;
        #pragma unroll 2
        for (int i = 0; i < 8; ++i) {
            int ko = grp * 8 + i;
            const float* ws = (ko < 16 ? Wr : Wl) + (size_t)((ko & 15) * 8) * 128 + col;
            short8 hi, lo;
            #pragma unroll
            for (int j = 0; j < 8; ++j) {
                float f = ws[(size_t)j * 128];
                unsigned short h1 = f2bf(f);
                unsigned short h2 = f2bf(f - bf2f(h1));
                hi[j] = (short)h1; lo[j] = (short)h2;
            }
            *reinterpret_cast<short8*>(&Whi[ko][col]) = hi;
            *reinterpret_cast<short8*>(&Wlo[ko][col]) = lo;
        }
    }

    f32x4 acc[2][4];
    #pragma unroll
    for (int i = 0; i < 2; ++i)
        #pragma unroll
        for (int c = 0; c < 4; ++c) acc[i][c] = f32x4{0.f, 0.f, 0.f, 0.f};

    // staging: thread t stages row rs = t>>2, k-oct ck = t&3 of each 32-k step
    const int rs = t >> 2, ck = t & 3;
    const int m_st = m0 + rs;
    const int g_st = m_st >> L2NS, n_st = m_st & (NS - 1);
    const float* xrow = FIRST ? (X + (size_t)m_st * F)
                              : (A + (size_t)g_st * 32768 + (size_t)(128 + n_st) * F);
    const float* arow = A + (size_t)g_st * 32768 + (size_t)n_st * F;

    for (int kt = 0; kt < 8; ++kt) {
        __syncthreads();  // prev-iter readers done (kt=0: also fences W pack)
        {
            const float* srow = ((kt < 4) ? (xrow + kt * 32) : (arow + (kt - 4) * 32)) + ck * 8;
            float4 fa = *(const float4*)srow;
            float4 fb = *(const float4*)(srow + 4);
            float vv[8] = {fa.x, fa.y, fa.z, fa.w, fb.x, fb.y, fb.z, fb.w};
            short8 h1, h2;
            #pragma unroll
            for (int j = 0; j < 8; ++j) {
                float f = vv[j];
                unsigned short a1 = f2bf(f);
                unsigned short a2 = f2bf(f - bf2f(a1));
                h1[j] = (short)a1; h2[j] = (short)a2;
            }
            *reinterpret_cast<short8*>(&Afs[0][ck][rs]) = h1;
            *reinterpret_cast<short8*>(&Afs[1][ck][rs]) = h2;
        }
        __syncthreads();

        short8 a1f[2], a2f[2];
        #pragma unroll
        for (int mt = 0; mt < 2; ++mt) {
            int row = wr * 32 + mt * 16 + l15;
            a1f[mt] = *reinterpret_cast<const short8*>(&Afs[0][lko][row]);
            a2f[mt] = *reinterpret_cast<const short8*>(&Afs[1][lko][row]);
        }
        const int kog = kt * 4 + lko;
        #pragma unroll
        for (int ct = 0; ct < 4; ++ct) {
            int col = wc * 64 + ct * 16 + l15;
            short8 w1 = *reinterpret_cast<const short8*>(&Whi[kog][col]);
            short8 w2 = *reinterpret_cast<const short8*>(&Wlo[kog][col]);
            #pragma unroll
            for (int mt = 0; mt < 2; ++mt) {
                acc[mt][ct] = __builtin_amdgcn_mfma_f32_16x16x32_bf16(a1f[mt], w1, acc[mt][ct], 0, 0, 0);
                acc[mt][ct] = __builtin_amdgcn_mfma_f32_16x16x32_bf16(a2f[mt], w1, acc[mt][ct], 0, 0, 0);
                acc[mt][ct] = __builtin_amdgcn_mfma_f32_16x16x32_bf16(a1f[mt], w2, acc[mt][ct], 0, 0, 0);
            }
        }
    }

    // epilogue: D col=lane&15 (per ct), row=(lane>>4)*4+reg
    #pragma unroll
    for (int ct = 0; ct < 4; ++ct) {
        int col = wc * 64 + ct * 16 + l15;
        float bv = bias[col];
        #pragma unroll
        for (int mt = 0; mt < 2; ++mt) {
            int r0 = m0 + wr * 32 + mt * 16 + lko * 4;
            #pragma unroll
            for (int r = 0; r < 4; ++r) {
                int m = r0 + r;
                int gg = m >> L2NS, nn = m & (NS - 1);
                A[(size_t)gg * 32768 + (size_t)nn * F + col] = fmaxf(acc[mt][ct][r] + bv, 0.f);
            }
        }
    }
}

// -------------------- top-k pool + readout + cmap update (1024 threads) --------------------
template<int N, int K, int STAGE>
__global__ __launch_bounds__(1024) void k_pool(float* __restrict__ A,
                                               float* __restrict__ R,
                                               int* __restrict__ cmap,
                                               const float* __restrict__ wp) {
    __shared__ float sc[N];
    __shared__ unsigned long long keys[N];
    __shared__ float hp[K * F];
    __shared__ int sel[K];
    __shared__ int inv[N];
    __shared__ float wn[F];
    __shared__ float gates[K];
    __shared__ float pmx[8 * F];
    __shared__ float psm[8 * F];
    __shared__ float snorm_s;
    const int g = blockIdx.x, t = threadIdx.x;
    const float* h = A + (size_t)g * 32768;
    const int lane = t & 63, wv16 = t >> 6;

    if (t < 64) {
        float v = wp[t] * wp[t] + wp[t + 64] * wp[t + 64];
        #pragma unroll
        for (int o = 32; o; o >>= 1) v += __shfl_xor(v, o);
        if (t == 0) snorm_s = sqrtf(v);
    }
    __syncthreads();
    if (t < 128) wn[t] = wp[t] / snorm_s;
    __syncthreads();

    {
        const int r16 = lane >> 4, l16 = lane & 15;
        float4 w0 = *(const float4*)&wn[l16 * 8];
        float4 w1 = *(const float4*)&wn[l16 * 8 + 4];
        #pragma unroll
        for (int n0 = 0; n0 < N; n0 += 64) {
            int r = n0 + wv16 * 4 + r16;
            const float* hr = h + (size_t)r * F + l16 * 8;
            float4 v0 = *(const float4*)hr;
            float4 v1 = *(const float4*)(hr + 4);
            float p = v0.x * w0.x + v0.y * w0.y + v0.z * w0.z + v0.w * w0.w
                    + v1.x * w1.x + v1.y * w1.y + v1.z * w1.z + v1.w * w1.w;
            p += __shfl_xor(p, 1); p += __shfl_xor(p, 2);
            p += __shfl_xor(p, 4); p += __shfl_xor(p, 8);
            if (l16 == 0) sc[r] = p;
        }
    }
    __syncthreads();

    if (t < N) {
        unsigned u = __float_as_uint(sc[t]);
        u = (u & 0x80000000u) ? ~u : (u | 0x80000000u);
        keys[t] = ((unsigned long long)u << 32) | (unsigned)(~t);
    }
    __syncthreads();
    for (int kk = 2; kk <= N; kk <<= 1) {
        for (int j = kk >> 1; j > 0; j >>= 1) {
            if (t < N) {
                int ixj = t ^ j;
                if (ixj > t) {
                    unsigned long long a = keys[t], b = keys[ixj];
                    bool up = (t & kk) == 0;
                    if (up ? (a < b) : (a > b)) { keys[t] = b; keys[ixj] = a; }
                }
            }
            __syncthreads();
        }
    }

    if (t < K) sel[t] = (int)(~(unsigned)keys[t]);
    if (t < N) inv[t] = -1;
    __syncthreads();
    if (t < K) {
        inv[sel[t]] = t;
        gates[t] = tanhf(sc[sel[t]]);
    }
    __syncthreads();
    if (t < 256) {
        int c = (STAGE == 1) ? t : cmap[g * 256 + t];
        cmap[g * 256 + t] = (c >= 0) ? inv[c] : -1;
    }

    {
        const int f = t & 127, seg = t >> 7;
        float mx = -INFINITY, sm = 0.f;
        for (int j = seg; j < K; j += 8) {
            float v = h[(size_t)sel[j] * F + f] * gates[j];
            hp[j * F + f] = v;
            mx = fmaxf(mx, v);
            sm += v;
        }
        pmx[seg * F + f] = mx;
        psm[seg * F + f] = sm;
    }
    __syncthreads();

    if (t < 128) {
        float m = -INFINITY, s = 0.f;
        #pragma unroll
        for (int q = 0; q < 8; ++q) {
            m = fmaxf(m, pmx[q * F + t]);
            s += psm[q * F + t];
        }
        R[(size_t)g * 768 + (STAGE - 1) * 256 + t] = m;
        R[(size_t)g * 768 + (STAGE - 1) * 256 + 128 + t] = s * (1.0f / K);
    }

    if (STAGE < 3) {
        float4* dst = (float4*)(A + (size_t)g * 32768 + 128 * F);
        const float4* srcp = (const float4*)hp;
        for (int i = t; i < K * F / 4; i += 1024) dst[i] = srcp[i];
    }
}

// -------------------- final MLP + log_softmax (split-K, 1024 threads) --------------------
__global__ __launch_bounds__(1024) void k_mlp(const float* __restrict__ R,
                                              const float* __restrict__ W1, const float* __restrict__ b1,
                                              const float* __restrict__ W2, const float* __restrict__ b2,
                                              const float* __restrict__ W3, const float* __restrict__ b3,
                                              float* __restrict__ out) {
    __shared__ float z[768];
    __shared__ float part[8][128];
    __shared__ float z2[128];
    __shared__ float z3[64];
    __shared__ float lg[10];
    __shared__ float lse;
    const int g = blockIdx.x, t = threadIdx.x;

    if (t < 768) z[t] = R[(size_t)g * 768 + t];
    __syncthreads();

    {
        const int f = t & 127, seg = t >> 7;
        float acc = 0.f;
        const float* w = W1 + (size_t)(seg * 96) * 128 + f;
        const float* zz = z + seg * 96;
        #pragma unroll 8
        for (int k = 0; k < 96; ++k) acc = fmaf(zz[k], w[(size_t)k * 128], acc);
        part[seg][f] = acc;
    }
    __syncthreads();
    if (t < 128) {
        float a = b1[t];
        #pragma unroll
        for (int q = 0; q < 8; ++q) a += part[q][t];
        z2[t] = fmaxf(a, 0.f);
    }
    __syncthreads();

    if (t < 512) {
        const int f = t & 63, seg = t >> 6;
        float acc = 0.f;
        const float* w = W2 + (size_t)(seg * 16) * 64 + f;
        const float* zz = z2 + seg * 16;
        #pragma unroll
        for (int k = 0; k < 16; ++k) acc = fmaf(zz[k], w[(size_t)k * 64], acc);
        part[seg][f] = acc;
    }
    __syncthreads();
    if (t < 64) {
        float a = b2[t];
        #pragma unroll
        for (int q = 0; q < 8; ++q) a += part[q][t];
        z3[t] = fmaxf(a, 0.f);
    }
    __syncthreads();

    if (t < 10) {
        float a3 = b3[t];
        #pragma unroll 8
        for (int k = 0; k < 64; ++k) a3 = fmaf(z3[k], W3[(size_t)k * 10 + t], a3);
        lg[t] = a3;
    }
    __syncthreads();

    if (t == 0) {
        float m = lg[0];
        for (int c = 1; c < 10; ++c) m = fmaxf(m, lg[c]);
        float s = 0.f;
        for (int c = 0; c < 10; ++c) s += expf(lg[c] - m);
        lse = m + logf(s);
    }
    __syncthreads();
    if (t < 10) out[(size_t)g * 10 + t] = lg[t] - lse;
}

extern "C" void kernel_launch(void* const* d_in, const int* in_sizes, int n_in,
                              void* d_out, int out_size, void* d_ws, size_t ws_size,
                              hipStream_t stream) {
    (void)in_sizes; (void)n_in; (void)out_size; (void)ws_size;
    const float* x    = (const float*)d_in[0];
    const int*   src  = (const int*)d_in[1];
    const int*   dst  = (const int*)d_in[2];
    const float* Wr1  = (const float*)d_in[3];
    const float* Wrel1= (const float*)d_in[4];
    const float* b1   = (const float*)d_in[5];
    const float* wp1  = (const float*)d_in[6];
    const float* Wr2  = (const float*)d_in[7];
    const float* Wrel2= (const float*)d_in[8];
    const float* b2   = (const float*)d_in[9];
    const float* wp2  = (const float*)d_in[10];
    const float* Wr3  = (const float*)d_in[11];
    const float* Wrel3= (const float*)d_in[12];
    const float* b3   = (const float*)d_in[13];
    const float* wp3  = (const float*)d_in[14];
    const float* L1w  = (const float*)d_in[15];
    const float* L1b  = (const float*)d_in[16];
    const float* L2w  = (const float*)d_in[17];
    const float* L2b  = (const float*)d_in[18];
    const float* L3w  = (const float*)d_in[19];
    const float* L3b  = (const float*)d_in[20];

    float* A    = (float*)d_ws;                                       // G x 256 x 128 f32
    int*   cmap = (int*)((char*)d_ws + (size_t)G * 32768 * 4);        // G x 256 i32
    float* R    = (float*)((char*)d_ws + (size_t)G * 32768 * 4 + (size_t)G * 256 * 4);  // G x 768 f32
    float* out  = (float*)d_out;

    // stage 1
    k_agg<256, 128, false><<<G * 2, 256, 0, stream>>>(x, src, dst, nullptr, A);
    k_gemm<256, true><<<512, 512, 0, stream>>>(x, A, Wr1, Wrel1, b1);
    k_pool<256, 128, 1><<<G, 1024, 0, stream>>>(A, R, cmap, wp1);
    // stage 2
    k_agg<128, 128, true><<<G, 256, 0, stream>>>(x, src, dst, cmap, A);
    k_gemm<128, false><<<256, 512, 0, stream>>>(nullptr, A, Wr2, Wrel2, b2);
    k_pool<128, 64, 2><<<G, 1024, 0, stream>>>(A, R, cmap, wp2);
    // stage 3
    k_agg<64, 64, true><<<G, 256, 0, stream>>>(x, src, dst, cmap, A);
    k_gemm<64, false><<<128, 512, 0, stream>>>(nullptr, A, Wr3, Wrel3, b3);
    k_pool<64, 32, 3><<<G, 1024, 0, stream>>>(A, R, cmap, wp3);
    // head
    k_mlp<<<G, 1024, 0, stream>>>(R, L1w, L1b, L2w, L2b, L3w, L3b, out);
}